// Round 3
// baseline (235.906 us; speedup 1.0000x reference)
//
#include <hip/hip_runtime.h>
#include <hip/hip_bf16.h>

#define T_LEN 2048
#define HID 2048
#define NH 16
#define NKV 4
#define HD 128
#define QKV_COLS 3072   // (16 + 2*4) * 128

typedef __attribute__((ext_vector_type(8))) short bf16x8;
typedef __attribute__((ext_vector_type(4))) float f32x4;

static __device__ __forceinline__ ushort f2bf(float f) {
  __hip_bfloat16 h = __float2bfloat16(f);
  return *reinterpret_cast<ushort*>(&h);
}
static __device__ __forceinline__ float bf2f(ushort u) {
  union { unsigned int i; float f; } v;
  v.i = ((unsigned int)u) << 16;
  return v.f;
}

// async global->LDS DMA, 16 bytes per lane (lane-linear LDS destination)
static __device__ __forceinline__ void async_copy16(const ushort* g, ushort* l) {
  __builtin_amdgcn_global_load_lds(
      (const __attribute__((address_space(1))) unsigned int*)g,
      (__attribute__((address_space(3))) unsigned int*)l, 16, 0, 0);
}

// ---------------------------------------------------------------------------
// Fused prep: blocks [0,4096): cast hidden f32->bf16
//             blocks [4096,5632): transpose+cast w_qkv -> wqkvT
//             blocks [5632,6144): RoPE cos/sin table
// ---------------------------------------------------------------------------
__global__ __launch_bounds__(256) void prep(
    const float* __restrict__ hidden, ushort* __restrict__ hb,
    const float* __restrict__ w_qkv, ushort* __restrict__ wqkvT,
    const int* __restrict__ positions, float2* __restrict__ tbl) {
  __shared__ float t[64][65];
  const int b = blockIdx.x;
  const int tid = threadIdx.x;
  if (b < 4096) {
    int idx = (b * 256 + tid) * 4;
    float4 v = *(const float4*)(hidden + idx);
    ushort4 o;
    o.x = f2bf(v.x); o.y = f2bf(v.y); o.z = f2bf(v.z); o.w = f2bf(v.w);
    *(ushort4*)(hb + idx) = o;
  } else if (b < 5632) {
    const int tb = b - 4096;
    const int bk = (tb & 31) * 64, bn = (tb >> 5) * 64;   // K=2048, N=3072
    const int c = tid & 63;
#pragma unroll
    for (int i = 0; i < 16; ++i) {
      int r = (tid >> 6) + i * 4;
      t[r][c] = w_qkv[(size_t)(bk + r) * QKV_COLS + bn + c];
    }
    __syncthreads();
#pragma unroll
    for (int i = 0; i < 16; ++i) {
      int r = (tid >> 6) + i * 4;
      wqkvT[(size_t)(bn + r) * HID + bk + c] = f2bf(t[c][r]);
    }
  } else {
    const int rb = b - 5632;
    const int tt = rb * 4 + (tid >> 6), j = tid & 63;
    double inv_freq = pow(1000000.0, -(double)(2 * j) / 128.0);
    double ang = (double)positions[tt] * inv_freq;
    double s, c2;
    sincos(ang, &s, &c2);
    tbl[(size_t)tt * 64 + j] = make_float2((float)c2, (float)s);
  }
}

// ---------------------------------------------------------------------------
// W [K][N] fp32  ->  WT [N][K] bf16   (still used standalone for w_o)
// ---------------------------------------------------------------------------
__global__ __launch_bounds__(256) void transpose_cast(
    const float* __restrict__ W, ushort* __restrict__ WT, int K, int N) {
  __shared__ float t[64][65];
  const int bk = blockIdx.x * 64, bn = blockIdx.y * 64;
  const int tid = threadIdx.x;
  const int c = tid & 63;
#pragma unroll
  for (int i = 0; i < 16; ++i) {
    int r = (tid >> 6) + i * 4;
    t[r][c] = W[(size_t)(bk + r) * N + bn + c];
  }
  __syncthreads();
#pragma unroll
  for (int i = 0; i < 16; ++i) {
    int r = (tid >> 6) + i * 4;
    WT[(size_t)(bn + r) * K + bk + c] = f2bf(t[c][r]);
  }
}

// ---------------------------------------------------------------------------
// bf16 MFMA GEMM-BT: C[M][N] = A[M][K] @ BT[N][K]^T, fp32 accum.
// Tile 64(M)x128(N), BK=64, 256 thr = 4 waves (wave tile 32x64).
// 2-phase double-buffered pipeline (T3-minimum recipe).
// ---------------------------------------------------------------------------
template <bool OUT_BF16>
__global__ __launch_bounds__(256, 3) void gemm_bt(
    const ushort* __restrict__ A, const ushort* __restrict__ BT,
    void* __restrict__ C, int M, int N, int K) {
  __shared__ __align__(16) ushort lds[2][1536 * 8];
  const int tid = threadIdx.x;
  const int bm = blockIdx.y * 64, bn = blockIdx.x * 128;
  const int wave = tid >> 6, lane = tid & 63;
  const int lr = lane & 15, lq = lane >> 4;
  const int wm = (wave & 1) * 32, wn = (wave >> 1) * 64;

  f32x4 acc[2][4];
#pragma unroll
  for (int i = 0; i < 2; ++i)
#pragma unroll
    for (int j = 0; j < 4; ++j) {
      acc[i][j][0] = 0.f; acc[i][j][1] = 0.f;
      acc[i][j][2] = 0.f; acc[i][j][3] = 0.f;
    }

  auto stage = [&](int k0, int buf) {
#pragma unroll
    for (int it = 0; it < 2; ++it) {
      int c = it * 256 + tid;
      int row = c >> 3, sl = c & 7, kc = sl ^ (row & 7);
      async_copy16(A + (size_t)(bm + row) * K + k0 + kc * 8, &lds[buf][c * 8]);
    }
#pragma unroll
    for (int it = 0; it < 4; ++it) {
      int c = it * 256 + tid;
      int row = c >> 3, sl = c & 7, kc = sl ^ (row & 7);
      async_copy16(BT + (size_t)(bn + row) * K + k0 + kc * 8,
                   &lds[buf][(512 + c) * 8]);
    }
  };

  stage(0, 0);
  __syncthreads();
  int cur = 0;
  for (int k0 = 0; k0 < K; k0 += 64) {
    if (k0 + 64 < K) stage(k0 + 64, cur ^ 1);
#pragma unroll
    for (int ks = 0; ks < 2; ++ks) {
      bf16x8 af[2], bfr[4];
#pragma unroll
      for (int mi = 0; mi < 2; ++mi) {
        int row = wm + mi * 16 + lr, kc = ks * 4 + lq;
        af[mi] = *(const bf16x8*)&lds[cur][(row * 8 + (kc ^ (row & 7))) * 8];
      }
#pragma unroll
      for (int ni = 0; ni < 4; ++ni) {
        int row = wn + ni * 16 + lr, kc = ks * 4 + lq;
        bfr[ni] =
            *(const bf16x8*)&lds[cur][(512 + row * 8 + (kc ^ (row & 7))) * 8];
      }
#pragma unroll
      for (int mi = 0; mi < 2; ++mi)
#pragma unroll
        for (int ni = 0; ni < 4; ++ni)
          acc[mi][ni] = __builtin_amdgcn_mfma_f32_16x16x32_bf16(
              af[mi], bfr[ni], acc[mi][ni], 0, 0, 0);
    }
    __syncthreads();   // drains next tile's loads + fences reads of lds[cur]
    cur ^= 1;
  }

#pragma unroll
  for (int mi = 0; mi < 2; ++mi)
#pragma unroll
    for (int ni = 0; ni < 4; ++ni)
#pragma unroll
      for (int r = 0; r < 4; ++r) {
        size_t row = bm + wm + mi * 16 + lq * 4 + r;
        size_t col = bn + wn + ni * 16 + lr;
        if (OUT_BF16)
          ((ushort*)C)[row * N + col] = f2bf(acc[mi][ni][r]);
        else
          ((float*)C)[row * N + col] = acc[mi][ni][r];
      }
}

// ---------------------------------------------------------------------------
// gemm1, same 2-phase pipeline, with fused epilogues:
//   heads 0..15 (q): rope + 1/sqrt(128) scale -> qkvb
//   heads 16..19 (k): rope -> qkvb
//   heads 20..23 (v): TRANSPOSED write directly into vt.
// ---------------------------------------------------------------------------
__global__ __launch_bounds__(256, 3) void gemm_qkv(
    const ushort* __restrict__ A, const ushort* __restrict__ BT,
    ushort* __restrict__ qkvb, ushort* __restrict__ vt,
    const float2* __restrict__ tbl, int M, int N, int K) {
  __shared__ __align__(16) ushort lds[2][1536 * 8];
  const int tid = threadIdx.x;
  const int bm = blockIdx.y * 64, bn = blockIdx.x * 128;
  const int wave = tid >> 6, lane = tid & 63;
  const int lr = lane & 15, lq = lane >> 4;
  const int wm = (wave & 1) * 32, wn = (wave >> 1) * 64;

  f32x4 acc[2][4];
#pragma unroll
  for (int i = 0; i < 2; ++i)
#pragma unroll
    for (int j = 0; j < 4; ++j) {
      acc[i][j][0] = 0.f; acc[i][j][1] = 0.f;
      acc[i][j][2] = 0.f; acc[i][j][3] = 0.f;
    }

  auto stage = [&](int k0, int buf) {
#pragma unroll
    for (int it = 0; it < 2; ++it) {
      int c = it * 256 + tid;
      int row = c >> 3, sl = c & 7, kc = sl ^ (row & 7);
      async_copy16(A + (size_t)(bm + row) * K + k0 + kc * 8, &lds[buf][c * 8]);
    }
#pragma unroll
    for (int it = 0; it < 4; ++it) {
      int c = it * 256 + tid;
      int row = c >> 3, sl = c & 7, kc = sl ^ (row & 7);
      async_copy16(BT + (size_t)(bn + row) * K + k0 + kc * 8,
                   &lds[buf][(512 + c) * 8]);
    }
  };

  stage(0, 0);
  __syncthreads();
  int cur = 0;
  for (int k0 = 0; k0 < K; k0 += 64) {
    if (k0 + 64 < K) stage(k0 + 64, cur ^ 1);
#pragma unroll
    for (int ks = 0; ks < 2; ++ks) {
      bf16x8 af[2], bfr[4];
#pragma unroll
      for (int mi = 0; mi < 2; ++mi) {
        int row = wm + mi * 16 + lr, kc = ks * 4 + lq;
        af[mi] = *(const bf16x8*)&lds[cur][(row * 8 + (kc ^ (row & 7))) * 8];
      }
#pragma unroll
      for (int ni = 0; ni < 4; ++ni) {
        int row = wn + ni * 16 + lr, kc = ks * 4 + lq;
        bfr[ni] =
            *(const bf16x8*)&lds[cur][(512 + row * 8 + (kc ^ (row & 7))) * 8];
      }
#pragma unroll
      for (int mi = 0; mi < 2; ++mi)
#pragma unroll
        for (int ni = 0; ni < 4; ++ni)
          acc[mi][ni] = __builtin_amdgcn_mfma_f32_16x16x32_bf16(
              af[mi], bfr[ni], acc[mi][ni], 0, 0, 0);
    }
    __syncthreads();
    cur ^= 1;
  }

  const int head = bn >> 7;
  ushort* ep = &lds[0][0];   // 64 x 130 bf16 tile (8320 <= 12288 ushorts)
  if (head < 20) {
    // ---- q/k head: rope via LDS round trip
#pragma unroll
    for (int mi = 0; mi < 2; ++mi)
#pragma unroll
      for (int ni = 0; ni < 4; ++ni)
#pragma unroll
        for (int r = 0; r < 4; ++r)
          ep[(wm + mi * 16 + lq * 4 + r) * 130 + wn + ni * 16 + lr] =
              f2bf(acc[mi][ni][r]);
    __syncthreads();

    const float qs = (head < NH) ? 0.08838834764831845f : 1.0f;
#pragma unroll
    for (int it = 0; it < 16; ++it) {
      int idx = it * 256 + tid;        // 64 rows x 64 pairs
      int row = idx >> 6, j = idx & 63;
      float x1 = bf2f(ep[row * 130 + j]);
      float x2 = bf2f(ep[row * 130 + 64 + j]);
      float2 cs = tbl[(size_t)(bm + row) * 64 + j];
      qkvb[(size_t)(bm + row) * QKV_COLS + bn + j] =
          f2bf((x1 * cs.x - x2 * cs.y) * qs);
      qkvb[(size_t)(bm + row) * QKV_COLS + bn + 64 + j] =
          f2bf((x2 * cs.x + x1 * cs.y) * qs);
    }
  } else {
    // ---- v head: transposed write into vt[vd][t] via LDS round trip
#pragma unroll
    for (int mi = 0; mi < 2; ++mi)
#pragma unroll
      for (int ni = 0; ni < 4; ++ni)
#pragma unroll
        for (int r = 0; r < 4; ++r)
          ep[(wm + mi * 16 + lq * 4 + r) * 130 + wn + ni * 16 + lr] =
              f2bf(acc[mi][ni][r]);
    __syncthreads();

    const int vd0 = bn - 2560;
#pragma unroll
    for (int it = 0; it < 8; ++it) {
      int idx = it * 256 + tid;        // 128 vd x 16 t-groups of 4
      int vd = idx >> 4, tg = (idx & 15) * 4;
      ushort4 w;
      w.x = ep[(tg + 0) * 130 + vd];
      w.y = ep[(tg + 1) * 130 + vd];
      w.z = ep[(tg + 2) * 130 + vd];
      w.w = ep[(tg + 3) * 130 + vd];
      *(ushort4*)&vt[(size_t)(vd0 + vd) * T_LEN + bm + tg] = w;
    }
  }
}

// ---------------------------------------------------------------------------
// Flash attention v6: NO K/V LDS staging — K/V are L2-resident (512 KB per
// kv-head each), so fragments load straight from global at their MFMA
// consumption point (same per-lane values the swizzled LDS cells held).
// Ps double-buffered -> ONE barrier per iteration. LDS 17.7 KB ->
// occupancy VGPR-bound (~4-5 blocks/CU vs 2).
// ---------------------------------------------------------------------------
__global__ __launch_bounds__(256, 4) void attn_mfma(
    const ushort* __restrict__ qkv, const ushort* __restrict__ vt,
    ushort* __restrict__ o, ushort* __restrict__ partials,
    float* __restrict__ ml) {
  int qt, h, k_begin, k_end, slot = -1;
  {
    const int i = blockIdx.x;
    if (i < 512) {
      qt = 31 - (i >> 5);
      const int rem = i & 31;
      h = rem >> 1;
      const int chunk = rem & 1;
      const int n = qt + 1, half = n >> 1;
      k_begin = chunk ? half : 0;
      k_end = chunk ? n : half;
      slot = ((qt - 16) * 16 + h) * 2 + chunk;
    } else {
      const int j = i - 512;
      qt = 15 - (j >> 4);
      h = j & 15;
      k_begin = 0;
      k_end = qt + 1;
    }
  }
  const int kh = h >> 2;
  const int tid = threadIdx.x;
  const int wave = tid >> 6, lane = tid & 63;
  const int lr = lane & 15, lq = lane >> 4;
  const int wq = wave >> 1, ws = wave & 1;

  __shared__ __align__(16) ushort Ps[2][8 * 67 * 8];
  __shared__ float l_sh[64][2];

  bf16x8 qf[2][4];
  {
    const ushort* qbase =
        qkv + (size_t)(qt * 64 + wq * 32 + lr) * QKV_COLS + h * HD + lq * 8;
#pragma unroll
    for (int mi = 0; mi < 2; ++mi)
#pragma unroll
      for (int kk = 0; kk < 4; ++kk)
        qf[mi][kk] = *(const bf16x8*)(qbase + (size_t)mi * 16 * QKV_COLS + kk * 32);
  }

  float l_part[2][4];
#pragma unroll
  for (int mi = 0; mi < 2; ++mi)
#pragma unroll
    for (int r = 0; r < 4; ++r) l_part[mi][r] = 0.f;
  f32x4 o_acc[4][2];
#pragma unroll
  for (int qi = 0; qi < 4; ++qi)
#pragma unroll
    for (int di = 0; di < 2; ++di) {
      o_acc[qi][di][0] = 0.f; o_acc[qi][di][1] = 0.f;
      o_acc[qi][di][2] = 0.f; o_acc[qi][di][3] = 0.f;
    }

  // per-lane K row base (row s = ws*32 + ni*16 + lr of each k-tile)
  const ushort* kbase0 = qkv + 2048 + kh * HD + (size_t)(ws * 32 + lr) * QKV_COLS;
  // per-lane V row base (row d = wave*32 + di*16 + lr of vt)
  const ushort* vbase0 = vt + (size_t)(kh * HD + wave * 32 + lr) * T_LEN;

  int pb = 0;
  for (int kt = k_begin; kt < k_end; ++kt) {
    // ---- QK^T: K fragments direct from global (L2)
    f32x4 s_acc[2][2];
#pragma unroll
    for (int mi = 0; mi < 2; ++mi)
#pragma unroll
      for (int ni = 0; ni < 2; ++ni) {
        s_acc[mi][ni][0] = 0.f; s_acc[mi][ni][1] = 0.f;
        s_acc[mi][ni][2] = 0.f; s_acc[mi][ni][3] = 0.f;
      }
    {
      const ushort* kb = kbase0 + (size_t)(kt * 64) * QKV_COLS + lq * 8;
#pragma unroll
      for (int kk = 0; kk < 4; ++kk) {
        bf16x8 kf[2];
#pragma unroll
        for (int ni = 0; ni < 2; ++ni)
          kf[ni] = *(const bf16x8*)(kb + (size_t)(ni * 16) * QKV_COLS + kk * 32);
#pragma unroll
        for (int mi = 0; mi < 2; ++mi)
#pragma unroll
          for (int ni = 0; ni < 2; ++ni)
            s_acc[mi][ni] = __builtin_amdgcn_mfma_f32_16x16x32_bf16(
                qf[mi][kk], kf[ni], s_acc[mi][ni], 0, 0, 0);
      }
    }

    if (kt == qt) {
#pragma unroll
      for (int mi = 0; mi < 2; ++mi)
#pragma unroll
        for (int ni = 0; ni < 2; ++ni)
#pragma unroll
          for (int r = 0; r < 4; ++r)
            if (ws * 32 + ni * 16 + lr > wq * 32 + mi * 16 + lq * 4 + r)
              s_acc[mi][ni][r] = -1e30f;
    }

#pragma unroll
    for (int mi = 0; mi < 2; ++mi)
#pragma unroll
      for (int ni = 0; ni < 2; ++ni)
#pragma unroll
        for (int r = 0; r < 4; ++r) {
          float p = __expf(s_acc[mi][ni][r]);
          l_part[mi][r] += p;
          int s = ws * 32 + ni * 16 + lr;
          int q = wq * 32 + mi * 16 + lq * 4 + r;
          Ps[pb][((s >> 3) * 67 + q) * 8 + (s & 7)] = f2bf(p);
        }
    __syncthreads();   // Ps[pb] visible; 2-buffer distance covers reuse hazard

    // ---- PV: V fragments direct from global (L2)
    {
      const ushort* vb = vbase0 + kt * 64 + lq * 8;
#pragma unroll
      for (int ss = 0; ss < 2; ++ss) {
        bf16x8 vf[2];
#pragma unroll
        for (int di = 0; di < 2; ++di)
          vf[di] = *(const bf16x8*)(vb + (size_t)(di * 16) * T_LEN + ss * 32);
#pragma unroll
        for (int qi = 0; qi < 4; ++qi) {
          bf16x8 pf =
              *(const bf16x8*)&Ps[pb][((ss * 4 + lq) * 67 + qi * 16 + lr) * 8];
#pragma unroll
          for (int di = 0; di < 2; ++di)
            o_acc[qi][di] = __builtin_amdgcn_mfma_f32_16x16x32_bf16(
                pf, vf[di], o_acc[qi][di], 0, 0, 0);
        }
      }
    }
    pb ^= 1;
  }

#pragma unroll
  for (int mi = 0; mi < 2; ++mi)
#pragma unroll
    for (int r = 0; r < 4; ++r) {
      float v = l_part[mi][r];
#pragma unroll
      for (int off = 1; off < 16; off <<= 1) v += __shfl_xor(v, off, 16);
      l_part[mi][r] = v;
    }
  if (lr == 0) {
#pragma unroll
    for (int mi = 0; mi < 2; ++mi)
#pragma unroll
      for (int r = 0; r < 4; ++r)
        l_sh[wq * 32 + mi * 16 + lq * 4 + r][ws] = l_part[mi][r];
  }
  __syncthreads();

  if (slot < 0) {
    ushort* ob = o + (size_t)(qt * 64) * (NH * HD) + h * HD + wave * 32;
#pragma unroll
    for (int qi = 0; qi < 4; ++qi)
#pragma unroll
      for (int r = 0; r < 4; ++r) {
        int q = qi * 16 + lq * 4 + r;
        float inv = 1.f / (l_sh[q][0] + l_sh[q][1]);
#pragma unroll
        for (int di = 0; di < 2; ++di)
          ob[(size_t)q * (NH * HD) + di * 16 + lr] =
              f2bf(o_acc[qi][di][r] * inv);
      }
  } else {
    ushort* pb2 = partials + (size_t)slot * 64 * HD + wave * 32;
#pragma unroll
    for (int qi = 0; qi < 4; ++qi)
#pragma unroll
      for (int r = 0; r < 4; ++r) {
        int q = qi * 16 + lq * 4 + r;
#pragma unroll
        for (int di = 0; di < 2; ++di)
          pb2[(size_t)q * HD + di * 16 + lr] = f2bf(o_acc[qi][di][r]);
      }
    if (tid < 64) ml[(size_t)slot * 64 + tid] = l_sh[tid][0] + l_sh[tid][1];
  }
}

// ---------------------------------------------------------------------------
// Combine the two key-range chunks for qt >= 16 (m=0: plain sum).
// ---------------------------------------------------------------------------
__global__ __launch_bounds__(256) void attn_reduce(
    const ushort* __restrict__ partials, const float* __restrict__ ml,
    ushort* __restrict__ o) {
  const int bi = blockIdx.x;
  const int qt = 16 + (bi >> 4), h = bi & 15;
  const int s0 = ((qt - 16) * 16 + h) * 2;
  const int tid = threadIdx.x;
  const int row = tid >> 2;
  const int dq = (tid & 3) * 32;

  float l0 = ml[(size_t)s0 * 64 + row];
  float l1 = ml[(size_t)(s0 + 1) * 64 + row];
  float inv = 1.f / (l0 + l1);

  const ushort* p0 = partials + ((size_t)s0 * 64 + row) * HD + dq;
  const ushort* p1 = partials + ((size_t)(s0 + 1) * 64 + row) * HD + dq;
  ushort* ob = o + (size_t)(qt * 64 + row) * (NH * HD) + h * HD + dq;
#pragma unroll
  for (int k = 0; k < 32; ++k)
    ob[k] = f2bf((bf2f(p0[k]) + bf2f(p1[k])) * inv);
}

// ---------------------------------------------------------------------------
extern "C" void kernel_launch(void* const* d_in, const int* in_sizes, int n_in,
                              void* d_out, int out_size, void* d_ws,
                              size_t ws_size, hipStream_t stream) {
  const float* hidden = (const float*)d_in[0];
  const float* w_qkv  = (const float*)d_in[1];
  const float* w_o    = (const float*)d_in[2];
  const int* positions = (const int*)d_in[3];
  float* out = (float*)d_out;

  ushort* ws = (ushort*)d_ws;
  ushort* hb    = ws;                    // 2048*2048  (dead after gemm1 -> ob)
  ushort* wqkvT = ws + 4194304;          // 3072*2048  (-> partials -> woT)
  ushort* qkvb  = wqkvT + 6291456;       // 2048*3072  (v-cols never written)
  ushort* vtb   = qkvb + 6291456;        // 512*2048
  float*  mlb   = (float*)(vtb + 1048576);        // 512*64 fp32 = 128 KB
  float2* tbl   = (float2*)(mlb + 32768);         // 2048*64 float2 = 1 MB
  ushort* ob       = hb;
  ushort* partials = wqkvT;
  ushort* woT      = wqkvT;

  // prep: cast (4096 blocks) + w_qkv transpose (1536) + rope table (512)
  prep<<<6144, 256, 0, stream>>>(hidden, hb, w_qkv, wqkvT, positions, tbl);

  gemm_qkv<<<dim3(QKV_COLS / 128, T_LEN / 64), 256, 0, stream>>>(
      hb, wqkvT, qkvb, vtb, tbl, T_LEN, QKV_COLS, HID);

  attn_mfma<<<768, 256, 0, stream>>>(qkvb, vtb, ob, partials, mlb);
  attn_reduce<<<256, 256, 0, stream>>>(partials, mlb, ob);

  transpose_cast<<<dim3(HID / 64, HID / 64), 256, 0, stream>>>(
      w_o, woT, HID, HID);

  gemm_bt<false><<<dim3(HID / 128, T_LEN / 64), 256, 0, stream>>>(
      ob, woT, out, T_LEN, HID, NH * HD);
}

// Round 4
// 222.002 us; speedup vs baseline: 1.0626x; 1.0626x over previous
//
#include <hip/hip_runtime.h>
#include <hip/hip_bf16.h>

#define T_LEN 2048
#define HID 2048
#define NH 16
#define NKV 4
#define HD 128
#define QKV_COLS 3072   // (16 + 2*4) * 128

typedef __attribute__((ext_vector_type(8))) short bf16x8;
typedef __attribute__((ext_vector_type(4))) float f32x4;

static __device__ __forceinline__ ushort f2bf(float f) {
  __hip_bfloat16 h = __float2bfloat16(f);
  return *reinterpret_cast<ushort*>(&h);
}
static __device__ __forceinline__ float bf2f(ushort u) {
  union { unsigned int i; float f; } v;
  v.i = ((unsigned int)u) << 16;
  return v.f;
}

// async global->LDS DMA, 16 bytes per lane (lane-linear LDS destination)
static __device__ __forceinline__ void async_copy16(const ushort* g, ushort* l) {
  __builtin_amdgcn_global_load_lds(
      (const __attribute__((address_space(1))) unsigned int*)g,
      (__attribute__((address_space(3))) unsigned int*)l, 16, 0, 0);
}

// ---------------------------------------------------------------------------
// Fused prep: blocks [0,4096): cast hidden f32->bf16
//             blocks [4096,5632): transpose+cast w_qkv -> wqkvT
//             blocks [5632,6144): RoPE cos/sin table
// ---------------------------------------------------------------------------
__global__ __launch_bounds__(256) void prep(
    const float* __restrict__ hidden, ushort* __restrict__ hb,
    const float* __restrict__ w_qkv, ushort* __restrict__ wqkvT,
    const int* __restrict__ positions, float2* __restrict__ tbl) {
  __shared__ float t[64][65];
  const int b = blockIdx.x;
  const int tid = threadIdx.x;
  if (b < 4096) {
    int idx = (b * 256 + tid) * 4;
    float4 v = *(const float4*)(hidden + idx);
    ushort4 o;
    o.x = f2bf(v.x); o.y = f2bf(v.y); o.z = f2bf(v.z); o.w = f2bf(v.w);
    *(ushort4*)(hb + idx) = o;
  } else if (b < 5632) {
    const int tb = b - 4096;
    const int bk = (tb & 31) * 64, bn = (tb >> 5) * 64;   // K=2048, N=3072
    const int c = tid & 63;
#pragma unroll
    for (int i = 0; i < 16; ++i) {
      int r = (tid >> 6) + i * 4;
      t[r][c] = w_qkv[(size_t)(bk + r) * QKV_COLS + bn + c];
    }
    __syncthreads();
#pragma unroll
    for (int i = 0; i < 16; ++i) {
      int r = (tid >> 6) + i * 4;
      wqkvT[(size_t)(bn + r) * HID + bk + c] = f2bf(t[c][r]);
    }
  } else {
    const int rb = b - 5632;
    const int tt = rb * 4 + (tid >> 6), j = tid & 63;
    double inv_freq = pow(1000000.0, -(double)(2 * j) / 128.0);
    double ang = (double)positions[tt] * inv_freq;
    double s, c2;
    sincos(ang, &s, &c2);
    tbl[(size_t)tt * 64 + j] = make_float2((float)c2, (float)s);
  }
}

// ---------------------------------------------------------------------------
// W [K][N] fp32  ->  WT [N][K] bf16   (still used standalone for w_o)
// ---------------------------------------------------------------------------
__global__ __launch_bounds__(256) void transpose_cast(
    const float* __restrict__ W, ushort* __restrict__ WT, int K, int N) {
  __shared__ float t[64][65];
  const int bk = blockIdx.x * 64, bn = blockIdx.y * 64;
  const int tid = threadIdx.x;
  const int c = tid & 63;
#pragma unroll
  for (int i = 0; i < 16; ++i) {
    int r = (tid >> 6) + i * 4;
    t[r][c] = W[(size_t)(bk + r) * N + bn + c];
  }
  __syncthreads();
#pragma unroll
  for (int i = 0; i < 16; ++i) {
    int r = (tid >> 6) + i * 4;
    WT[(size_t)(bn + r) * K + bk + c] = f2bf(t[c][r]);
  }
}

// ---------------------------------------------------------------------------
// bf16 MFMA GEMM-BT, m97 structure: 128x128 tile, BK=64, 4 waves (64x64
// wave tile, acc 4x4), global_load_lds into XOR-swizzled cells, 1-phase
// 2-barrier K-loop. LDS 32 KB; VGPR-capped 3 blocks/CU.
// ---------------------------------------------------------------------------
template <bool OUT_BF16>
__global__ __launch_bounds__(256, 3) void gemm_bt(
    const ushort* __restrict__ A, const ushort* __restrict__ BT,
    void* __restrict__ C, int M, int N, int K) {
  __shared__ __align__(16) ushort lds[2048 * 8];   // A cells 0..1023, B 1024..2047
  const int tid = threadIdx.x;
  const int bm = blockIdx.y * 128, bn = blockIdx.x * 128;
  const int wave = tid >> 6, lane = tid & 63;
  const int lr = lane & 15, lq = lane >> 4;
  const int wm = (wave & 1) * 64, wn = (wave >> 1) * 64;

  f32x4 acc[4][4];
#pragma unroll
  for (int i = 0; i < 4; ++i)
#pragma unroll
    for (int j = 0; j < 4; ++j) {
      acc[i][j][0] = 0.f; acc[i][j][1] = 0.f;
      acc[i][j][2] = 0.f; acc[i][j][3] = 0.f;
    }

  for (int k0 = 0; k0 < K; k0 += 64) {
#pragma unroll
    for (int it = 0; it < 4; ++it) {         // A: 128 rows x 64 cols
      int c = it * 256 + tid;
      int row = c >> 3, sl = c & 7, kc = sl ^ (row & 7);
      async_copy16(A + (size_t)(bm + row) * K + k0 + kc * 8, &lds[c * 8]);
    }
#pragma unroll
    for (int it = 0; it < 4; ++it) {         // B: 128 rows x 64 cols
      int c = it * 256 + tid;
      int row = c >> 3, sl = c & 7, kc = sl ^ (row & 7);
      async_copy16(BT + (size_t)(bn + row) * K + k0 + kc * 8,
                   &lds[(1024 + c) * 8]);
    }
    __syncthreads();

#pragma unroll
    for (int ks = 0; ks < 2; ++ks) {
      bf16x8 af[4], bfr[4];
#pragma unroll
      for (int mi = 0; mi < 4; ++mi) {
        int row = wm + mi * 16 + lr, kc = ks * 4 + lq;
        af[mi] = *(const bf16x8*)&lds[(row * 8 + (kc ^ (row & 7))) * 8];
      }
#pragma unroll
      for (int ni = 0; ni < 4; ++ni) {
        int row = wn + ni * 16 + lr, kc = ks * 4 + lq;
        bfr[ni] = *(const bf16x8*)&lds[(1024 + row * 8 + (kc ^ (row & 7))) * 8];
      }
#pragma unroll
      for (int mi = 0; mi < 4; ++mi)
#pragma unroll
        for (int ni = 0; ni < 4; ++ni)
          acc[mi][ni] = __builtin_amdgcn_mfma_f32_16x16x32_bf16(
              af[mi], bfr[ni], acc[mi][ni], 0, 0, 0);
    }
    __syncthreads();
  }

#pragma unroll
  for (int mi = 0; mi < 4; ++mi)
#pragma unroll
    for (int ni = 0; ni < 4; ++ni)
#pragma unroll
      for (int r = 0; r < 4; ++r) {
        size_t row = bm + wm + mi * 16 + lq * 4 + r;
        size_t col = bn + wn + ni * 16 + lr;
        if (OUT_BF16)
          ((ushort*)C)[row * N + col] = f2bf(acc[mi][ni][r]);
        else
          ((float*)C)[row * N + col] = acc[mi][ni][r];
      }
}

// ---------------------------------------------------------------------------
// gemm1, same m97 128x128 structure, fused epilogues:
//   heads 0..15 (q): rope + 1/sqrt(128) scale -> qkvb
//   heads 16..19 (k): rope -> qkvb
//   heads 20..23 (v): TRANSPOSED write directly into vt.
// Epilogue round-trips through a 128x130 bf16 LDS tile (33 KB, unioned
// with the 32 KB staging buffer).
// ---------------------------------------------------------------------------
__global__ __launch_bounds__(256, 3) void gemm_qkv(
    const ushort* __restrict__ A, const ushort* __restrict__ BT,
    ushort* __restrict__ qkvb, ushort* __restrict__ vt,
    const float2* __restrict__ tbl, int M, int N, int K) {
  __shared__ __align__(16) ushort lds[16640];   // staging 16384; ep 128*130
  const int tid = threadIdx.x;
  const int bm = blockIdx.y * 128, bn = blockIdx.x * 128;
  const int wave = tid >> 6, lane = tid & 63;
  const int lr = lane & 15, lq = lane >> 4;
  const int wm = (wave & 1) * 64, wn = (wave >> 1) * 64;

  f32x4 acc[4][4];
#pragma unroll
  for (int i = 0; i < 4; ++i)
#pragma unroll
    for (int j = 0; j < 4; ++j) {
      acc[i][j][0] = 0.f; acc[i][j][1] = 0.f;
      acc[i][j][2] = 0.f; acc[i][j][3] = 0.f;
    }

  for (int k0 = 0; k0 < K; k0 += 64) {
#pragma unroll
    for (int it = 0; it < 4; ++it) {
      int c = it * 256 + tid;
      int row = c >> 3, sl = c & 7, kc = sl ^ (row & 7);
      async_copy16(A + (size_t)(bm + row) * K + k0 + kc * 8, &lds[c * 8]);
    }
#pragma unroll
    for (int it = 0; it < 4; ++it) {
      int c = it * 256 + tid;
      int row = c >> 3, sl = c & 7, kc = sl ^ (row & 7);
      async_copy16(BT + (size_t)(bn + row) * K + k0 + kc * 8,
                   &lds[(1024 + c) * 8]);
    }
    __syncthreads();

#pragma unroll
    for (int ks = 0; ks < 2; ++ks) {
      bf16x8 af[4], bfr[4];
#pragma unroll
      for (int mi = 0; mi < 4; ++mi) {
        int row = wm + mi * 16 + lr, kc = ks * 4 + lq;
        af[mi] = *(const bf16x8*)&lds[(row * 8 + (kc ^ (row & 7))) * 8];
      }
#pragma unroll
      for (int ni = 0; ni < 4; ++ni) {
        int row = wn + ni * 16 + lr, kc = ks * 4 + lq;
        bfr[ni] = *(const bf16x8*)&lds[(1024 + row * 8 + (kc ^ (row & 7))) * 8];
      }
#pragma unroll
      for (int mi = 0; mi < 4; ++mi)
#pragma unroll
        for (int ni = 0; ni < 4; ++ni)
          acc[mi][ni] = __builtin_amdgcn_mfma_f32_16x16x32_bf16(
              af[mi], bfr[ni], acc[mi][ni], 0, 0, 0);
    }
    __syncthreads();
  }

  const int head = bn >> 7;
  ushort* ep = lds;   // 128 x 130 bf16 tile
#pragma unroll
  for (int mi = 0; mi < 4; ++mi)
#pragma unroll
    for (int ni = 0; ni < 4; ++ni)
#pragma unroll
      for (int r = 0; r < 4; ++r)
        ep[(wm + mi * 16 + lq * 4 + r) * 130 + wn + ni * 16 + lr] =
            f2bf(acc[mi][ni][r]);
  __syncthreads();

  if (head < 20) {
    // ---- q/k head: rope (pairs j, j+64 within the 128-wide head tile)
    const float qs = (head < NH) ? 0.08838834764831845f : 1.0f;
#pragma unroll
    for (int it = 0; it < 32; ++it) {
      int idx = it * 256 + tid;        // 128 rows x 64 pairs
      int row = idx >> 6, j = idx & 63;
      float x1 = bf2f(ep[row * 130 + j]);
      float x2 = bf2f(ep[row * 130 + 64 + j]);
      float2 cs = tbl[(size_t)(bm + row) * 64 + j];
      qkvb[(size_t)(bm + row) * QKV_COLS + bn + j] =
          f2bf((x1 * cs.x - x2 * cs.y) * qs);
      qkvb[(size_t)(bm + row) * QKV_COLS + bn + 64 + j] =
          f2bf((x2 * cs.x + x1 * cs.y) * qs);
    }
  } else {
    // ---- v head: transposed write into vt[vd][t]
    const int vd0 = bn - 2560;
#pragma unroll
    for (int it = 0; it < 16; ++it) {
      int idx = it * 256 + tid;        // 128 vd x 32 t-groups of 4
      int vd = idx >> 5, tg = (idx & 31) * 4;
      ushort4 w;
      w.x = ep[(tg + 0) * 130 + vd];
      w.y = ep[(tg + 1) * 130 + vd];
      w.z = ep[(tg + 2) * 130 + vd];
      w.w = ep[(tg + 3) * 130 + vd];
      *(ushort4*)&vt[(size_t)(vd0 + vd) * T_LEN + bm + tg] = w;
    }
  }
}

// ---------------------------------------------------------------------------
// Flash attention v4 (reverted to R1 best, 41.7 us): m=0 softmax, 2x2 wave
// QK split, register Q, single-buffered DMA-staged swizzled K/V, PV d-split,
// split-K 768 blocks, 3 blocks/CU.
// ---------------------------------------------------------------------------
__global__ __launch_bounds__(256, 3) void attn_mfma(
    const ushort* __restrict__ qkv, const ushort* __restrict__ vt,
    ushort* __restrict__ o, ushort* __restrict__ partials,
    float* __restrict__ ml) {
  int qt, h, k_begin, k_end, slot = -1;
  {
    const int i = blockIdx.x;
    if (i < 512) {
      qt = 31 - (i >> 5);
      const int rem = i & 31;
      h = rem >> 1;
      const int chunk = rem & 1;
      const int n = qt + 1, half = n >> 1;
      k_begin = chunk ? half : 0;
      k_end = chunk ? n : half;
      slot = ((qt - 16) * 16 + h) * 2 + chunk;
    } else {
      const int j = i - 512;
      qt = 15 - (j >> 4);
      h = j & 15;
      k_begin = 0;
      k_end = qt + 1;
    }
  }
  const int kh = h >> 2;
  const int tid = threadIdx.x;
  const int wave = tid >> 6, lane = tid & 63;
  const int lr = lane & 15, lq = lane >> 4;
  const int wq = wave >> 1, ws = wave & 1;

  __shared__ __align__(16) ushort KsL[1024 * 8];
  __shared__ __align__(16) ushort VtsL[1024 * 8];
  __shared__ __align__(16) ushort Ps[8 * 67 * 8];
  __shared__ float l_sh[64][2];

  bf16x8 qf[2][4];
  {
    const ushort* qbase =
        qkv + (size_t)(qt * 64 + wq * 32 + lr) * QKV_COLS + h * HD + lq * 8;
#pragma unroll
    for (int mi = 0; mi < 2; ++mi)
#pragma unroll
      for (int kk = 0; kk < 4; ++kk)
        qf[mi][kk] = *(const bf16x8*)(qbase + (size_t)mi * 16 * QKV_COLS + kk * 32);
  }

  float l_part[2][4];
#pragma unroll
  for (int mi = 0; mi < 2; ++mi)
#pragma unroll
    for (int r = 0; r < 4; ++r) l_part[mi][r] = 0.f;
  f32x4 o_acc[4][2];
#pragma unroll
  for (int qi = 0; qi < 4; ++qi)
#pragma unroll
    for (int di = 0; di < 2; ++di) {
      o_acc[qi][di][0] = 0.f; o_acc[qi][di][1] = 0.f;
      o_acc[qi][di][2] = 0.f; o_acc[qi][di][3] = 0.f;
    }

  for (int kt = k_begin; kt < k_end; ++kt) {
    __syncthreads();

    {
      const ushort* kbase = qkv + 2048 + kh * HD;
#pragma unroll
      for (int it = 0; it < 4; ++it) {
        int c = it * 256 + tid;
        int s = c >> 4, sl = c & 15, dg = sl ^ (s & 15);
        async_copy16(kbase + (size_t)(kt * 64 + s) * QKV_COLS + dg * 8,
                     &KsL[c * 8]);
      }
    }
    {
      const ushort* vbase = vt + (size_t)(kh * HD) * T_LEN + kt * 64;
#pragma unroll
      for (int it = 0; it < 4; ++it) {
        int c = it * 256 + tid;
        int d = c >> 3, sl = c & 7, sc = sl ^ (d & 7);
        async_copy16(vbase + (size_t)d * T_LEN + sc * 8, &VtsL[c * 8]);
      }
    }
    __syncthreads();

    f32x4 s_acc[2][2];
#pragma unroll
    for (int mi = 0; mi < 2; ++mi)
#pragma unroll
      for (int ni = 0; ni < 2; ++ni) {
        s_acc[mi][ni][0] = 0.f; s_acc[mi][ni][1] = 0.f;
        s_acc[mi][ni][2] = 0.f; s_acc[mi][ni][3] = 0.f;
      }
#pragma unroll
    for (int kk = 0; kk < 4; ++kk) {
      bf16x8 kf[2];
#pragma unroll
      for (int ni = 0; ni < 2; ++ni) {
        int s = ws * 32 + ni * 16 + lr;
        kf[ni] = *(const bf16x8*)&KsL[(s * 16 + ((kk * 4 + lq) ^ (s & 15))) * 8];
      }
#pragma unroll
      for (int mi = 0; mi < 2; ++mi)
#pragma unroll
        for (int ni = 0; ni < 2; ++ni)
          s_acc[mi][ni] = __builtin_amdgcn_mfma_f32_16x16x32_bf16(
              qf[mi][kk], kf[ni], s_acc[mi][ni], 0, 0, 0);
    }

    if (kt == qt) {
#pragma unroll
      for (int mi = 0; mi < 2; ++mi)
#pragma unroll
        for (int ni = 0; ni < 2; ++ni)
#pragma unroll
          for (int r = 0; r < 4; ++r)
            if (ws * 32 + ni * 16 + lr > wq * 32 + mi * 16 + lq * 4 + r)
              s_acc[mi][ni][r] = -1e30f;
    }

#pragma unroll
    for (int mi = 0; mi < 2; ++mi)
#pragma unroll
      for (int ni = 0; ni < 2; ++ni)
#pragma unroll
        for (int r = 0; r < 4; ++r) {
          float p = __expf(s_acc[mi][ni][r]);
          l_part[mi][r] += p;
          int s = ws * 32 + ni * 16 + lr;
          int q = wq * 32 + mi * 16 + lq * 4 + r;
          Ps[((s >> 3) * 67 + q) * 8 + (s & 7)] = f2bf(p);
        }
    __syncthreads();

#pragma unroll
    for (int ss = 0; ss < 2; ++ss) {
      bf16x8 vf[2];
#pragma unroll
      for (int di = 0; di < 2; ++di) {
        int d = wave * 32 + di * 16 + lr, sc = ss * 4 + lq;
        vf[di] = *(const bf16x8*)&VtsL[(d * 8 + (sc ^ (d & 7))) * 8];
      }
#pragma unroll
      for (int qi = 0; qi < 4; ++qi) {
        bf16x8 pf = *(const bf16x8*)&Ps[((ss * 4 + lq) * 67 + qi * 16 + lr) * 8];
#pragma unroll
        for (int di = 0; di < 2; ++di)
          o_acc[qi][di] = __builtin_amdgcn_mfma_f32_16x16x32_bf16(
              pf, vf[di], o_acc[qi][di], 0, 0, 0);
      }
    }
  }

#pragma unroll
  for (int mi = 0; mi < 2; ++mi)
#pragma unroll
    for (int r = 0; r < 4; ++r) {
      float v = l_part[mi][r];
#pragma unroll
      for (int off = 1; off < 16; off <<= 1) v += __shfl_xor(v, off, 16);
      l_part[mi][r] = v;
    }
  if (lr == 0) {
#pragma unroll
    for (int mi = 0; mi < 2; ++mi)
#pragma unroll
      for (int r = 0; r < 4; ++r)
        l_sh[wq * 32 + mi * 16 + lq * 4 + r][ws] = l_part[mi][r];
  }
  __syncthreads();

  if (slot < 0) {
    ushort* ob = o + (size_t)(qt * 64) * (NH * HD) + h * HD + wave * 32;
#pragma unroll
    for (int qi = 0; qi < 4; ++qi)
#pragma unroll
      for (int r = 0; r < 4; ++r) {
        int q = qi * 16 + lq * 4 + r;
        float inv = 1.f / (l_sh[q][0] + l_sh[q][1]);
#pragma unroll
        for (int di = 0; di < 2; ++di)
          ob[(size_t)q * (NH * HD) + di * 16 + lr] =
              f2bf(o_acc[qi][di][r] * inv);
      }
  } else {
    ushort* pb = partials + (size_t)slot * 64 * HD + wave * 32;
#pragma unroll
    for (int qi = 0; qi < 4; ++qi)
#pragma unroll
      for (int r = 0; r < 4; ++r) {
        int q = qi * 16 + lq * 4 + r;
#pragma unroll
        for (int di = 0; di < 2; ++di)
          pb[(size_t)q * HD + di * 16 + lr] = f2bf(o_acc[qi][di][r]);
      }
    if (tid < 64) ml[(size_t)slot * 64 + tid] = l_sh[tid][0] + l_sh[tid][1];
  }
}

// ---------------------------------------------------------------------------
// Combine the two key-range chunks for qt >= 16 (m=0: plain sum).
// ---------------------------------------------------------------------------
__global__ __launch_bounds__(256) void attn_reduce(
    const ushort* __restrict__ partials, const float* __restrict__ ml,
    ushort* __restrict__ o) {
  const int bi = blockIdx.x;
  const int qt = 16 + (bi >> 4), h = bi & 15;
  const int s0 = ((qt - 16) * 16 + h) * 2;
  const int tid = threadIdx.x;
  const int row = tid >> 2;
  const int dq = (tid & 3) * 32;

  float l0 = ml[(size_t)s0 * 64 + row];
  float l1 = ml[(size_t)(s0 + 1) * 64 + row];
  float inv = 1.f / (l0 + l1);

  const ushort* p0 = partials + ((size_t)s0 * 64 + row) * HD + dq;
  const ushort* p1 = partials + ((size_t)(s0 + 1) * 64 + row) * HD + dq;
  ushort* ob = o + (size_t)(qt * 64 + row) * (NH * HD) + h * HD + dq;
#pragma unroll
  for (int k = 0; k < 32; ++k)
    ob[k] = f2bf((bf2f(p0[k]) + bf2f(p1[k])) * inv);
}

// ---------------------------------------------------------------------------
extern "C" void kernel_launch(void* const* d_in, const int* in_sizes, int n_in,
                              void* d_out, int out_size, void* d_ws,
                              size_t ws_size, hipStream_t stream) {
  const float* hidden = (const float*)d_in[0];
  const float* w_qkv  = (const float*)d_in[1];
  const float* w_o    = (const float*)d_in[2];
  const int* positions = (const int*)d_in[3];
  float* out = (float*)d_out;

  ushort* ws = (ushort*)d_ws;
  ushort* hb    = ws;                    // 2048*2048  (dead after gemm1 -> ob)
  ushort* wqkvT = ws + 4194304;          // 3072*2048  (-> partials -> woT)
  ushort* qkvb  = wqkvT + 6291456;       // 2048*3072  (v-cols never written)
  ushort* vtb   = qkvb + 6291456;        // 512*2048
  float*  mlb   = (float*)(vtb + 1048576);        // 512*64 fp32 = 128 KB
  float2* tbl   = (float2*)(mlb + 32768);         // 2048*64 float2 = 1 MB
  ushort* ob       = hb;
  ushort* partials = wqkvT;
  ushort* woT      = wqkvT;

  // prep: cast (4096 blocks) + w_qkv transpose (1536) + rope table (512)
  prep<<<6144, 256, 0, stream>>>(hidden, hb, w_qkv, wqkvT, positions, tbl);

  gemm_qkv<<<dim3(QKV_COLS / 128, T_LEN / 128), 256, 0, stream>>>(
      hb, wqkvT, qkvb, vtb, tbl, T_LEN, QKV_COLS, HID);

  attn_mfma<<<768, 256, 0, stream>>>(qkvb, vtb, ob, partials, mlb);
  attn_reduce<<<256, 256, 0, stream>>>(partials, mlb, ob);

  transpose_cast<<<dim3(HID / 64, HID / 64), 256, 0, stream>>>(
      w_o, woT, HID, HID);

  gemm_bt<false><<<dim3(HID / 128, T_LEN / 128), 256, 0, stream>>>(
      ob, woT, out, T_LEN, HID, NH * HD);
}

// Round 5
// 203.436 us; speedup vs baseline: 1.1596x; 1.0913x over previous
//
#include <hip/hip_runtime.h>
#include <hip/hip_bf16.h>

#define T_LEN 2048
#define HID 2048
#define NH 16
#define NKV 4
#define HD 128
#define QKV_COLS 3072   // (16 + 2*4) * 128

typedef __attribute__((ext_vector_type(8))) short bf16x8;
typedef __attribute__((ext_vector_type(4))) float f32x4;

static __device__ __forceinline__ ushort f2bf(float f) {
  __hip_bfloat16 h = __float2bfloat16(f);
  return *reinterpret_cast<ushort*>(&h);
}
static __device__ __forceinline__ float bf2f(ushort u) {
  union { unsigned int i; float f; } v;
  v.i = ((unsigned int)u) << 16;
  return v.f;
}

// async global->LDS DMA, 16 bytes per lane (lane-linear LDS destination)
static __device__ __forceinline__ void async_copy16(const ushort* g, ushort* l) {
  __builtin_amdgcn_global_load_lds(
      (const __attribute__((address_space(1))) unsigned int*)g,
      (__attribute__((address_space(3))) unsigned int*)l, 16, 0, 0);
}

// ---------------------------------------------------------------------------
// Fused prep: blocks [0,4096): cast hidden f32->bf16
//             blocks [4096,5632): transpose+cast w_qkv -> wqkvT
//             blocks [5632,6144): RoPE cos/sin table
// ---------------------------------------------------------------------------
__global__ __launch_bounds__(256) void prep(
    const float* __restrict__ hidden, ushort* __restrict__ hb,
    const float* __restrict__ w_qkv, ushort* __restrict__ wqkvT,
    const int* __restrict__ positions, float2* __restrict__ tbl) {
  __shared__ float t[64][65];
  const int b = blockIdx.x;
  const int tid = threadIdx.x;
  if (b < 4096) {
    int idx = (b * 256 + tid) * 4;
    float4 v = *(const float4*)(hidden + idx);
    ushort4 o;
    o.x = f2bf(v.x); o.y = f2bf(v.y); o.z = f2bf(v.z); o.w = f2bf(v.w);
    *(ushort4*)(hb + idx) = o;
  } else if (b < 5632) {
    const int tb = b - 4096;
    const int bk = (tb & 31) * 64, bn = (tb >> 5) * 64;   // K=2048, N=3072
    const int c = tid & 63;
#pragma unroll
    for (int i = 0; i < 16; ++i) {
      int r = (tid >> 6) + i * 4;
      t[r][c] = w_qkv[(size_t)(bk + r) * QKV_COLS + bn + c];
    }
    __syncthreads();
#pragma unroll
    for (int i = 0; i < 16; ++i) {
      int r = (tid >> 6) + i * 4;
      wqkvT[(size_t)(bn + r) * HID + bk + c] = f2bf(t[c][r]);
    }
  } else {
    const int rb = b - 5632;
    const int tt = rb * 4 + (tid >> 6), j = tid & 63;
    double inv_freq = pow(1000000.0, -(double)(2 * j) / 128.0);
    double ang = (double)positions[tt] * inv_freq;
    double s, c2;
    sincos(ang, &s, &c2);
    tbl[(size_t)tt * 64 + j] = make_float2((float)c2, (float)s);
  }
}

// ---------------------------------------------------------------------------
// W [K][N] fp32  ->  WT [N][K] bf16   (standalone for w_o; must run after
// attn because woT aliases the partials buffer)
// ---------------------------------------------------------------------------
__global__ __launch_bounds__(256) void transpose_cast(
    const float* __restrict__ W, ushort* __restrict__ WT, int K, int N) {
  __shared__ float t[64][65];
  const int bk = blockIdx.x * 64, bn = blockIdx.y * 64;
  const int tid = threadIdx.x;
  const int c = tid & 63;
#pragma unroll
  for (int i = 0; i < 16; ++i) {
    int r = (tid >> 6) + i * 4;
    t[r][c] = W[(size_t)(bk + r) * N + bn + c];
  }
  __syncthreads();
#pragma unroll
  for (int i = 0; i < 16; ++i) {
    int r = (tid >> 6) + i * 4;
    WT[(size_t)(bn + r) * K + bk + c] = f2bf(t[c][r]);
  }
}

// ---------------------------------------------------------------------------
// bf16 MFMA GEMM-BT: C[M][N] = A[M][K] @ BT[N][K]^T, fp32 accum.
// Tile 64(M)x128(N), BK=64, 256 thr = 4 waves (wave tile 32x64).
// 2-phase double-buffered pipeline (best measured config at this grid size:
// 512-768 blocks, 3 blocks/CU — R1 total 203.8 us; 128^2 tile starves the
// grid at 256-384 blocks and regressed, R4).
// ---------------------------------------------------------------------------
template <bool OUT_BF16>
__global__ __launch_bounds__(256, 3) void gemm_bt(
    const ushort* __restrict__ A, const ushort* __restrict__ BT,
    void* __restrict__ C, int M, int N, int K) {
  __shared__ __align__(16) ushort lds[2][1536 * 8];
  const int tid = threadIdx.x;
  const int bm = blockIdx.y * 64, bn = blockIdx.x * 128;
  const int wave = tid >> 6, lane = tid & 63;
  const int lr = lane & 15, lq = lane >> 4;
  const int wm = (wave & 1) * 32, wn = (wave >> 1) * 64;

  f32x4 acc[2][4];
#pragma unroll
  for (int i = 0; i < 2; ++i)
#pragma unroll
    for (int j = 0; j < 4; ++j) {
      acc[i][j][0] = 0.f; acc[i][j][1] = 0.f;
      acc[i][j][2] = 0.f; acc[i][j][3] = 0.f;
    }

  auto stage = [&](int k0, int buf) {
#pragma unroll
    for (int it = 0; it < 2; ++it) {
      int c = it * 256 + tid;
      int row = c >> 3, sl = c & 7, kc = sl ^ (row & 7);
      async_copy16(A + (size_t)(bm + row) * K + k0 + kc * 8, &lds[buf][c * 8]);
    }
#pragma unroll
    for (int it = 0; it < 4; ++it) {
      int c = it * 256 + tid;
      int row = c >> 3, sl = c & 7, kc = sl ^ (row & 7);
      async_copy16(BT + (size_t)(bn + row) * K + k0 + kc * 8,
                   &lds[buf][(512 + c) * 8]);
    }
  };

  stage(0, 0);
  __syncthreads();
  int cur = 0;
  for (int k0 = 0; k0 < K; k0 += 64) {
    if (k0 + 64 < K) stage(k0 + 64, cur ^ 1);
#pragma unroll
    for (int ks = 0; ks < 2; ++ks) {
      bf16x8 af[2], bfr[4];
#pragma unroll
      for (int mi = 0; mi < 2; ++mi) {
        int row = wm + mi * 16 + lr, kc = ks * 4 + lq;
        af[mi] = *(const bf16x8*)&lds[cur][(row * 8 + (kc ^ (row & 7))) * 8];
      }
#pragma unroll
      for (int ni = 0; ni < 4; ++ni) {
        int row = wn + ni * 16 + lr, kc = ks * 4 + lq;
        bfr[ni] =
            *(const bf16x8*)&lds[cur][(512 + row * 8 + (kc ^ (row & 7))) * 8];
      }
#pragma unroll
      for (int mi = 0; mi < 2; ++mi)
#pragma unroll
        for (int ni = 0; ni < 4; ++ni)
          acc[mi][ni] = __builtin_amdgcn_mfma_f32_16x16x32_bf16(
              af[mi], bfr[ni], acc[mi][ni], 0, 0, 0);
    }
    __syncthreads();   // drains next tile's loads + fences reads of lds[cur]
    cur ^= 1;
  }

#pragma unroll
  for (int mi = 0; mi < 2; ++mi)
#pragma unroll
    for (int ni = 0; ni < 4; ++ni)
#pragma unroll
      for (int r = 0; r < 4; ++r) {
        size_t row = bm + wm + mi * 16 + lq * 4 + r;
        size_t col = bn + wn + ni * 16 + lr;
        if (OUT_BF16)
          ((ushort*)C)[row * N + col] = f2bf(acc[mi][ni][r]);
        else
          ((float*)C)[row * N + col] = acc[mi][ni][r];
      }
}

// ---------------------------------------------------------------------------
// gemm1, same 2-phase pipeline, with fused epilogues:
//   heads 0..15 (q): rope + 1/sqrt(128) scale -> qkvb
//   heads 16..19 (k): rope -> qkvb
//   heads 20..23 (v): TRANSPOSED write directly into vt.
// ---------------------------------------------------------------------------
__global__ __launch_bounds__(256, 3) void gemm_qkv(
    const ushort* __restrict__ A, const ushort* __restrict__ BT,
    ushort* __restrict__ qkvb, ushort* __restrict__ vt,
    const float2* __restrict__ tbl, int M, int N, int K) {
  __shared__ __align__(16) ushort lds[2][1536 * 8];
  const int tid = threadIdx.x;
  const int bm = blockIdx.y * 64, bn = blockIdx.x * 128;
  const int wave = tid >> 6, lane = tid & 63;
  const int lr = lane & 15, lq = lane >> 4;
  const int wm = (wave & 1) * 32, wn = (wave >> 1) * 64;

  f32x4 acc[2][4];
#pragma unroll
  for (int i = 0; i < 2; ++i)
#pragma unroll
    for (int j = 0; j < 4; ++j) {
      acc[i][j][0] = 0.f; acc[i][j][1] = 0.f;
      acc[i][j][2] = 0.f; acc[i][j][3] = 0.f;
    }

  auto stage = [&](int k0, int buf) {
#pragma unroll
    for (int it = 0; it < 2; ++it) {
      int c = it * 256 + tid;
      int row = c >> 3, sl = c & 7, kc = sl ^ (row & 7);
      async_copy16(A + (size_t)(bm + row) * K + k0 + kc * 8, &lds[buf][c * 8]);
    }
#pragma unroll
    for (int it = 0; it < 4; ++it) {
      int c = it * 256 + tid;
      int row = c >> 3, sl = c & 7, kc = sl ^ (row & 7);
      async_copy16(BT + (size_t)(bn + row) * K + k0 + kc * 8,
                   &lds[buf][(512 + c) * 8]);
    }
  };

  stage(0, 0);
  __syncthreads();
  int cur = 0;
  for (int k0 = 0; k0 < K; k0 += 64) {
    if (k0 + 64 < K) stage(k0 + 64, cur ^ 1);
#pragma unroll
    for (int ks = 0; ks < 2; ++ks) {
      bf16x8 af[2], bfr[4];
#pragma unroll
      for (int mi = 0; mi < 2; ++mi) {
        int row = wm + mi * 16 + lr, kc = ks * 4 + lq;
        af[mi] = *(const bf16x8*)&lds[cur][(row * 8 + (kc ^ (row & 7))) * 8];
      }
#pragma unroll
      for (int ni = 0; ni < 4; ++ni) {
        int row = wn + ni * 16 + lr, kc = ks * 4 + lq;
        bfr[ni] =
            *(const bf16x8*)&lds[cur][(512 + row * 8 + (kc ^ (row & 7))) * 8];
      }
#pragma unroll
      for (int mi = 0; mi < 2; ++mi)
#pragma unroll
        for (int ni = 0; ni < 4; ++ni)
          acc[mi][ni] = __builtin_amdgcn_mfma_f32_16x16x32_bf16(
              af[mi], bfr[ni], acc[mi][ni], 0, 0, 0);
    }
    __syncthreads();
    cur ^= 1;
  }

  const int head = bn >> 7;
  ushort* ep = &lds[0][0];   // 64 x 130 bf16 tile (8320 <= 12288 ushorts)
  if (head < 20) {
    // ---- q/k head: rope via LDS round trip
#pragma unroll
    for (int mi = 0; mi < 2; ++mi)
#pragma unroll
      for (int ni = 0; ni < 4; ++ni)
#pragma unroll
        for (int r = 0; r < 4; ++r)
          ep[(wm + mi * 16 + lq * 4 + r) * 130 + wn + ni * 16 + lr] =
              f2bf(acc[mi][ni][r]);
    __syncthreads();

    const float qs = (head < NH) ? 0.08838834764831845f : 1.0f;
#pragma unroll
    for (int it = 0; it < 16; ++it) {
      int idx = it * 256 + tid;        // 64 rows x 64 pairs
      int row = idx >> 6, j = idx & 63;
      float x1 = bf2f(ep[row * 130 + j]);
      float x2 = bf2f(ep[row * 130 + 64 + j]);
      float2 cs = tbl[(size_t)(bm + row) * 64 + j];
      qkvb[(size_t)(bm + row) * QKV_COLS + bn + j] =
          f2bf((x1 * cs.x - x2 * cs.y) * qs);
      qkvb[(size_t)(bm + row) * QKV_COLS + bn + 64 + j] =
          f2bf((x2 * cs.x + x1 * cs.y) * qs);
    }
  } else {
    // ---- v head: transposed write into vt[vd][t] via LDS round trip
#pragma unroll
    for (int mi = 0; mi < 2; ++mi)
#pragma unroll
      for (int ni = 0; ni < 4; ++ni)
#pragma unroll
        for (int r = 0; r < 4; ++r)
          ep[(wm + mi * 16 + lq * 4 + r) * 130 + wn + ni * 16 + lr] =
              f2bf(acc[mi][ni][r]);
    __syncthreads();

    const int vd0 = bn - 2560;
#pragma unroll
    for (int it = 0; it < 8; ++it) {
      int idx = it * 256 + tid;        // 128 vd x 16 t-groups of 4
      int vd = idx >> 4, tg = (idx & 15) * 4;
      ushort4 w;
      w.x = ep[(tg + 0) * 130 + vd];
      w.y = ep[(tg + 1) * 130 + vd];
      w.z = ep[(tg + 2) * 130 + vd];
      w.w = ep[(tg + 3) * 130 + vd];
      *(ushort4*)&vt[(size_t)(vd0 + vd) * T_LEN + bm + tg] = w;
    }
  }
}

// ---------------------------------------------------------------------------
// Flash attention v4 + T5 setprio: m=0 softmax, 2x2 wave QK split, register
// Q, single-buffered DMA-staged swizzled K/V, PV d-split, split-K 768
// blocks, 3 blocks/CU. setprio(1) around MFMA clusters (m191: +4-7% attn).
// ---------------------------------------------------------------------------
__global__ __launch_bounds__(256, 3) void attn_mfma(
    const ushort* __restrict__ qkv, const ushort* __restrict__ vt,
    ushort* __restrict__ o, ushort* __restrict__ partials,
    float* __restrict__ ml) {
  int qt, h, k_begin, k_end, slot = -1;
  {
    const int i = blockIdx.x;
    if (i < 512) {
      qt = 31 - (i >> 5);
      const int rem = i & 31;
      h = rem >> 1;
      const int chunk = rem & 1;
      const int n = qt + 1, half = n >> 1;
      k_begin = chunk ? half : 0;
      k_end = chunk ? n : half;
      slot = ((qt - 16) * 16 + h) * 2 + chunk;
    } else {
      const int j = i - 512;
      qt = 15 - (j >> 4);
      h = j & 15;
      k_begin = 0;
      k_end = qt + 1;
    }
  }
  const int kh = h >> 2;
  const int tid = threadIdx.x;
  const int wave = tid >> 6, lane = tid & 63;
  const int lr = lane & 15, lq = lane >> 4;
  const int wq = wave >> 1, ws = wave & 1;

  __shared__ __align__(16) ushort KsL[1024 * 8];
  __shared__ __align__(16) ushort VtsL[1024 * 8];
  __shared__ __align__(16) ushort Ps[8 * 67 * 8];
  __shared__ float l_sh[64][2];

  bf16x8 qf[2][4];
  {
    const ushort* qbase =
        qkv + (size_t)(qt * 64 + wq * 32 + lr) * QKV_COLS + h * HD + lq * 8;
#pragma unroll
    for (int mi = 0; mi < 2; ++mi)
#pragma unroll
      for (int kk = 0; kk < 4; ++kk)
        qf[mi][kk] = *(const bf16x8*)(qbase + (size_t)mi * 16 * QKV_COLS + kk * 32);
  }

  float l_part[2][4];
#pragma unroll
  for (int mi = 0; mi < 2; ++mi)
#pragma unroll
    for (int r = 0; r < 4; ++r) l_part[mi][r] = 0.f;
  f32x4 o_acc[4][2];
#pragma unroll
  for (int qi = 0; qi < 4; ++qi)
#pragma unroll
    for (int di = 0; di < 2; ++di) {
      o_acc[qi][di][0] = 0.f; o_acc[qi][di][1] = 0.f;
      o_acc[qi][di][2] = 0.f; o_acc[qi][di][3] = 0.f;
    }

  for (int kt = k_begin; kt < k_end; ++kt) {
    __syncthreads();

    {
      const ushort* kbase = qkv + 2048 + kh * HD;
#pragma unroll
      for (int it = 0; it < 4; ++it) {
        int c = it * 256 + tid;
        int s = c >> 4, sl = c & 15, dg = sl ^ (s & 15);
        async_copy16(kbase + (size_t)(kt * 64 + s) * QKV_COLS + dg * 8,
                     &KsL[c * 8]);
      }
    }
    {
      const ushort* vbase = vt + (size_t)(kh * HD) * T_LEN + kt * 64;
#pragma unroll
      for (int it = 0; it < 4; ++it) {
        int c = it * 256 + tid;
        int d = c >> 3, sl = c & 7, sc = sl ^ (d & 7);
        async_copy16(vbase + (size_t)d * T_LEN + sc * 8, &VtsL[c * 8]);
      }
    }
    __syncthreads();

    f32x4 s_acc[2][2];
#pragma unroll
    for (int mi = 0; mi < 2; ++mi)
#pragma unroll
      for (int ni = 0; ni < 2; ++ni) {
        s_acc[mi][ni][0] = 0.f; s_acc[mi][ni][1] = 0.f;
        s_acc[mi][ni][2] = 0.f; s_acc[mi][ni][3] = 0.f;
      }
    __builtin_amdgcn_s_setprio(1);
#pragma unroll
    for (int kk = 0; kk < 4; ++kk) {
      bf16x8 kf[2];
#pragma unroll
      for (int ni = 0; ni < 2; ++ni) {
        int s = ws * 32 + ni * 16 + lr;
        kf[ni] = *(const bf16x8*)&KsL[(s * 16 + ((kk * 4 + lq) ^ (s & 15))) * 8];
      }
#pragma unroll
      for (int mi = 0; mi < 2; ++mi)
#pragma unroll
        for (int ni = 0; ni < 2; ++ni)
          s_acc[mi][ni] = __builtin_amdgcn_mfma_f32_16x16x32_bf16(
              qf[mi][kk], kf[ni], s_acc[mi][ni], 0, 0, 0);
    }
    __builtin_amdgcn_s_setprio(0);

    if (kt == qt) {
#pragma unroll
      for (int mi = 0; mi < 2; ++mi)
#pragma unroll
        for (int ni = 0; ni < 2; ++ni)
#pragma unroll
          for (int r = 0; r < 4; ++r)
            if (ws * 32 + ni * 16 + lr > wq * 32 + mi * 16 + lq * 4 + r)
              s_acc[mi][ni][r] = -1e30f;
    }

#pragma unroll
    for (int mi = 0; mi < 2; ++mi)
#pragma unroll
      for (int ni = 0; ni < 2; ++ni)
#pragma unroll
        for (int r = 0; r < 4; ++r) {
          float p = __expf(s_acc[mi][ni][r]);
          l_part[mi][r] += p;
          int s = ws * 32 + ni * 16 + lr;
          int q = wq * 32 + mi * 16 + lq * 4 + r;
          Ps[((s >> 3) * 67 + q) * 8 + (s & 7)] = f2bf(p);
        }
    __syncthreads();

    __builtin_amdgcn_s_setprio(1);
#pragma unroll
    for (int ss = 0; ss < 2; ++ss) {
      bf16x8 vf[2];
#pragma unroll
      for (int di = 0; di < 2; ++di) {
        int d = wave * 32 + di * 16 + lr, sc = ss * 4 + lq;
        vf[di] = *(const bf16x8*)&VtsL[(d * 8 + (sc ^ (d & 7))) * 8];
      }
#pragma unroll
      for (int qi = 0; qi < 4; ++qi) {
        bf16x8 pf = *(const bf16x8*)&Ps[((ss * 4 + lq) * 67 + qi * 16 + lr) * 8];
#pragma unroll
        for (int di = 0; di < 2; ++di)
          o_acc[qi][di] = __builtin_amdgcn_mfma_f32_16x16x32_bf16(
              pf, vf[di], o_acc[qi][di], 0, 0, 0);
      }
    }
    __builtin_amdgcn_s_setprio(0);
  }

#pragma unroll
  for (int mi = 0; mi < 2; ++mi)
#pragma unroll
    for (int r = 0; r < 4; ++r) {
      float v = l_part[mi][r];
#pragma unroll
      for (int off = 1; off < 16; off <<= 1) v += __shfl_xor(v, off, 16);
      l_part[mi][r] = v;
    }
  if (lr == 0) {
#pragma unroll
    for (int mi = 0; mi < 2; ++mi)
#pragma unroll
      for (int r = 0; r < 4; ++r)
        l_sh[wq * 32 + mi * 16 + lq * 4 + r][ws] = l_part[mi][r];
  }
  __syncthreads();

  if (slot < 0) {
    ushort* ob = o + (size_t)(qt * 64) * (NH * HD) + h * HD + wave * 32;
#pragma unroll
    for (int qi = 0; qi < 4; ++qi)
#pragma unroll
      for (int r = 0; r < 4; ++r) {
        int q = qi * 16 + lq * 4 + r;
        float inv = 1.f / (l_sh[q][0] + l_sh[q][1]);
#pragma unroll
        for (int di = 0; di < 2; ++di)
          ob[(size_t)q * (NH * HD) + di * 16 + lr] =
              f2bf(o_acc[qi][di][r] * inv);
      }
  } else {
    ushort* pb = partials + (size_t)slot * 64 * HD + wave * 32;
#pragma unroll
    for (int qi = 0; qi < 4; ++qi)
#pragma unroll
      for (int r = 0; r < 4; ++r) {
        int q = qi * 16 + lq * 4 + r;
#pragma unroll
        for (int di = 0; di < 2; ++di)
          pb[(size_t)q * HD + di * 16 + lr] = f2bf(o_acc[qi][di][r]);
      }
    if (tid < 64) ml[(size_t)slot * 64 + tid] = l_sh[tid][0] + l_sh[tid][1];
  }
}

// ---------------------------------------------------------------------------
// Combine the two key-range chunks for qt >= 16 (m=0: plain sum).
// Vectorized bf16x8 loads/stores (was 32 scalar ushort ops per thread).
// ---------------------------------------------------------------------------
__global__ __launch_bounds__(256) void attn_reduce(
    const ushort* __restrict__ partials, const float* __restrict__ ml,
    ushort* __restrict__ o) {
  const int bi = blockIdx.x;
  const int qt = 16 + (bi >> 4), h = bi & 15;
  const int s0 = ((qt - 16) * 16 + h) * 2;
  const int tid = threadIdx.x;
  const int row = tid >> 2;
  const int dq = (tid & 3) * 32;

  float l0 = ml[(size_t)s0 * 64 + row];
  float l1 = ml[(size_t)(s0 + 1) * 64 + row];
  float inv = 1.f / (l0 + l1);

  const ushort* p0 = partials + ((size_t)s0 * 64 + row) * HD + dq;
  const ushort* p1 = partials + ((size_t)(s0 + 1) * 64 + row) * HD + dq;
  ushort* ob = o + (size_t)(qt * 64 + row) * (NH * HD) + h * HD + dq;
#pragma unroll
  for (int v = 0; v < 4; ++v) {
    bf16x8 a = *(const bf16x8*)(p0 + v * 8);
    bf16x8 b = *(const bf16x8*)(p1 + v * 8);
    bf16x8 w;
#pragma unroll
    for (int k = 0; k < 8; ++k)
      w[k] = (short)f2bf((bf2f((ushort)a[k]) + bf2f((ushort)b[k])) * inv);
    *(bf16x8*)(ob + v * 8) = w;
  }
}

// ---------------------------------------------------------------------------
extern "C" void kernel_launch(void* const* d_in, const int* in_sizes, int n_in,
                              void* d_out, int out_size, void* d_ws,
                              size_t ws_size, hipStream_t stream) {
  const float* hidden = (const float*)d_in[0];
  const float* w_qkv  = (const float*)d_in[1];
  const float* w_o    = (const float*)d_in[2];
  const int* positions = (const int*)d_in[3];
  float* out = (float*)d_out;

  ushort* ws = (ushort*)d_ws;
  ushort* hb    = ws;                    // 2048*2048  (dead after gemm1 -> ob)
  ushort* wqkvT = ws + 4194304;          // 3072*2048  (-> partials -> woT)
  ushort* qkvb  = wqkvT + 6291456;       // 2048*3072  (v-cols never written)
  ushort* vtb   = qkvb + 6291456;        // 512*2048
  float*  mlb   = (float*)(vtb + 1048576);        // 512*64 fp32 = 128 KB
  float2* tbl   = (float2*)(mlb + 32768);         // 2048*64 float2 = 1 MB
  ushort* ob       = hb;
  ushort* partials = wqkvT;
  ushort* woT      = wqkvT;

  // prep: cast (4096 blocks) + w_qkv transpose (1536) + rope table (512)
  prep<<<6144, 256, 0, stream>>>(hidden, hb, w_qkv, wqkvT, positions, tbl);

  gemm_qkv<<<dim3(QKV_COLS / 128, T_LEN / 64), 256, 0, stream>>>(
      hb, wqkvT, qkvb, vtb, tbl, T_LEN, QKV_COLS, HID);

  attn_mfma<<<768, 256, 0, stream>>>(qkvb, vtb, ob, partials, mlb);
  attn_reduce<<<256, 256, 0, stream>>>(partials, mlb, ob);

  transpose_cast<<<dim3(HID / 64, HID / 64), 256, 0, stream>>>(
      w_o, woT, HID, HID);

  gemm_bt<false><<<dim3(HID / 128, T_LEN / 64), 256, 0, stream>>>(
      ob, woT, out, T_LEN, HID, NH * HD);
}

// Round 6
// 196.097 us; speedup vs baseline: 1.2030x; 1.0374x over previous
//
#include <hip/hip_runtime.h>
#include <hip/hip_bf16.h>

#define T_LEN 2048
#define HID 2048
#define NH 16
#define NKV 4
#define HD 128
#define QKV_COLS 3072   // (16 + 2*4) * 128

typedef __attribute__((ext_vector_type(8))) short bf16x8;
typedef __attribute__((ext_vector_type(4))) float f32x4;

static __device__ __forceinline__ ushort f2bf(float f) {
  __hip_bfloat16 h = __float2bfloat16(f);
  return *reinterpret_cast<ushort*>(&h);
}
static __device__ __forceinline__ float bf2f(ushort u) {
  union { unsigned int i; float f; } v;
  v.i = ((unsigned int)u) << 16;
  return v.f;
}

// async global->LDS DMA, 16 bytes per lane (lane-linear LDS destination)
static __device__ __forceinline__ void async_copy16(const ushort* g, ushort* l) {
  __builtin_amdgcn_global_load_lds(
      (const __attribute__((address_space(1))) unsigned int*)g,
      (__attribute__((address_space(3))) unsigned int*)l, 16, 0, 0);
}

// ---------------------------------------------------------------------------
// Fused prep: blocks [0,4096): cast hidden f32->bf16
//             blocks [4096,5632): transpose+cast w_qkv -> wqkvT
//             blocks [5632,6144): RoPE cos/sin table
//             blocks [6144,7168): transpose+cast w_o -> woT (fast path only;
//                                 grid=6144 in fallback skips these blocks)
// ---------------------------------------------------------------------------
__global__ __launch_bounds__(256) void prep(
    const float* __restrict__ hidden, ushort* __restrict__ hb,
    const float* __restrict__ w_qkv, ushort* __restrict__ wqkvT,
    const int* __restrict__ positions, float2* __restrict__ tbl,
    const float* __restrict__ w_o, ushort* __restrict__ woT) {
  __shared__ float t[64][65];
  const int b = blockIdx.x;
  const int tid = threadIdx.x;
  if (b < 4096) {
    int idx = (b * 256 + tid) * 4;
    float4 v = *(const float4*)(hidden + idx);
    ushort4 o;
    o.x = f2bf(v.x); o.y = f2bf(v.y); o.z = f2bf(v.z); o.w = f2bf(v.w);
    *(ushort4*)(hb + idx) = o;
  } else if (b < 5632) {
    const int tb = b - 4096;
    const int bk = (tb & 31) * 64, bn = (tb >> 5) * 64;   // K=2048, N=3072
    const int c = tid & 63;
#pragma unroll
    for (int i = 0; i < 16; ++i) {
      int r = (tid >> 6) + i * 4;
      t[r][c] = w_qkv[(size_t)(bk + r) * QKV_COLS + bn + c];
    }
    __syncthreads();
#pragma unroll
    for (int i = 0; i < 16; ++i) {
      int r = (tid >> 6) + i * 4;
      wqkvT[(size_t)(bn + r) * HID + bk + c] = f2bf(t[c][r]);
    }
  } else if (b < 6144) {
    const int rb = b - 5632;
    const int tt = rb * 4 + (tid >> 6), j = tid & 63;
    double inv_freq = pow(1000000.0, -(double)(2 * j) / 128.0);
    double ang = (double)positions[tt] * inv_freq;
    double s, c2;
    sincos(ang, &s, &c2);
    tbl[(size_t)tt * 64 + j] = make_float2((float)c2, (float)s);
  } else {
    const int tb = b - 6144;
    const int bk = (tb & 31) * 64, bn = (tb >> 5) * 64;   // K=N=2048
    const int c = tid & 63;
#pragma unroll
    for (int i = 0; i < 16; ++i) {
      int r = (tid >> 6) + i * 4;
      t[r][c] = w_o[(size_t)(bk + r) * HID + bn + c];
    }
    __syncthreads();
#pragma unroll
    for (int i = 0; i < 16; ++i) {
      int r = (tid >> 6) + i * 4;
      woT[(size_t)(bn + r) * HID + bk + c] = f2bf(t[c][r]);
    }
  }
}

// ---------------------------------------------------------------------------
// W [K][N] fp32  ->  WT [N][K] bf16   (fallback path for w_o; must run after
// attn_reduce because woT then aliases the partials buffer)
// ---------------------------------------------------------------------------
__global__ __launch_bounds__(256) void transpose_cast(
    const float* __restrict__ W, ushort* __restrict__ WT, int K, int N) {
  __shared__ float t[64][65];
  const int bk = blockIdx.x * 64, bn = blockIdx.y * 64;
  const int tid = threadIdx.x;
  const int c = tid & 63;
#pragma unroll
  for (int i = 0; i < 16; ++i) {
    int r = (tid >> 6) + i * 4;
    t[r][c] = W[(size_t)(bk + r) * N + bn + c];
  }
  __syncthreads();
#pragma unroll
  for (int i = 0; i < 16; ++i) {
    int r = (tid >> 6) + i * 4;
    WT[(size_t)(bn + r) * K + bk + c] = f2bf(t[c][r]);
  }
}

// ---------------------------------------------------------------------------
// bf16 MFMA GEMM-BT: C[M][N] = A[M][K] @ BT[N][K]^T, fp32 accum.
// Tile 64(M)x128(N), BK=64, 256 thr = 4 waves (wave tile 32x64).
// 2-phase double-buffered pipeline (best measured config at this grid size).
// ---------------------------------------------------------------------------
template <bool OUT_BF16>
__global__ __launch_bounds__(256, 3) void gemm_bt(
    const ushort* __restrict__ A, const ushort* __restrict__ BT,
    void* __restrict__ C, int M, int N, int K) {
  __shared__ __align__(16) ushort lds[2][1536 * 8];
  const int tid = threadIdx.x;
  const int bm = blockIdx.y * 64, bn = blockIdx.x * 128;
  const int wave = tid >> 6, lane = tid & 63;
  const int lr = lane & 15, lq = lane >> 4;
  const int wm = (wave & 1) * 32, wn = (wave >> 1) * 64;

  f32x4 acc[2][4];
#pragma unroll
  for (int i = 0; i < 2; ++i)
#pragma unroll
    for (int j = 0; j < 4; ++j) {
      acc[i][j][0] = 0.f; acc[i][j][1] = 0.f;
      acc[i][j][2] = 0.f; acc[i][j][3] = 0.f;
    }

  auto stage = [&](int k0, int buf) {
#pragma unroll
    for (int it = 0; it < 2; ++it) {
      int c = it * 256 + tid;
      int row = c >> 3, sl = c & 7, kc = sl ^ (row & 7);
      async_copy16(A + (size_t)(bm + row) * K + k0 + kc * 8, &lds[buf][c * 8]);
    }
#pragma unroll
    for (int it = 0; it < 4; ++it) {
      int c = it * 256 + tid;
      int row = c >> 3, sl = c & 7, kc = sl ^ (row & 7);
      async_copy16(BT + (size_t)(bn + row) * K + k0 + kc * 8,
                   &lds[buf][(512 + c) * 8]);
    }
  };

  stage(0, 0);
  __syncthreads();
  int cur = 0;
  for (int k0 = 0; k0 < K; k0 += 64) {
    if (k0 + 64 < K) stage(k0 + 64, cur ^ 1);
#pragma unroll
    for (int ks = 0; ks < 2; ++ks) {
      bf16x8 af[2], bfr[4];
#pragma unroll
      for (int mi = 0; mi < 2; ++mi) {
        int row = wm + mi * 16 + lr, kc = ks * 4 + lq;
        af[mi] = *(const bf16x8*)&lds[cur][(row * 8 + (kc ^ (row & 7))) * 8];
      }
#pragma unroll
      for (int ni = 0; ni < 4; ++ni) {
        int row = wn + ni * 16 + lr, kc = ks * 4 + lq;
        bfr[ni] =
            *(const bf16x8*)&lds[cur][(512 + row * 8 + (kc ^ (row & 7))) * 8];
      }
#pragma unroll
      for (int mi = 0; mi < 2; ++mi)
#pragma unroll
        for (int ni = 0; ni < 4; ++ni)
          acc[mi][ni] = __builtin_amdgcn_mfma_f32_16x16x32_bf16(
              af[mi], bfr[ni], acc[mi][ni], 0, 0, 0);
    }
    __syncthreads();   // drains next tile's loads + fences reads of lds[cur]
    cur ^= 1;
  }

#pragma unroll
  for (int mi = 0; mi < 2; ++mi)
#pragma unroll
    for (int ni = 0; ni < 4; ++ni)
#pragma unroll
      for (int r = 0; r < 4; ++r) {
        size_t row = bm + wm + mi * 16 + lq * 4 + r;
        size_t col = bn + wn + ni * 16 + lr;
        if (OUT_BF16)
          ((ushort*)C)[row * N + col] = f2bf(acc[mi][ni][r]);
        else
          ((float*)C)[row * N + col] = acc[mi][ni][r];
      }
}

// ---------------------------------------------------------------------------
// gemm1, same 2-phase pipeline, with fused epilogues:
//   heads 0..15 (q): rope + 1/sqrt(128) scale -> qkvb
//   heads 16..19 (k): rope -> qkvb
//   heads 20..23 (v): TRANSPOSED write directly into vt.
// ---------------------------------------------------------------------------
__global__ __launch_bounds__(256, 3) void gemm_qkv(
    const ushort* __restrict__ A, const ushort* __restrict__ BT,
    ushort* __restrict__ qkvb, ushort* __restrict__ vt,
    const float2* __restrict__ tbl, int M, int N, int K) {
  __shared__ __align__(16) ushort lds[2][1536 * 8];
  const int tid = threadIdx.x;
  const int bm = blockIdx.y * 64, bn = blockIdx.x * 128;
  const int wave = tid >> 6, lane = tid & 63;
  const int lr = lane & 15, lq = lane >> 4;
  const int wm = (wave & 1) * 32, wn = (wave >> 1) * 64;

  f32x4 acc[2][4];
#pragma unroll
  for (int i = 0; i < 2; ++i)
#pragma unroll
    for (int j = 0; j < 4; ++j) {
      acc[i][j][0] = 0.f; acc[i][j][1] = 0.f;
      acc[i][j][2] = 0.f; acc[i][j][3] = 0.f;
    }

  auto stage = [&](int k0, int buf) {
#pragma unroll
    for (int it = 0; it < 2; ++it) {
      int c = it * 256 + tid;
      int row = c >> 3, sl = c & 7, kc = sl ^ (row & 7);
      async_copy16(A + (size_t)(bm + row) * K + k0 + kc * 8, &lds[buf][c * 8]);
    }
#pragma unroll
    for (int it = 0; it < 4; ++it) {
      int c = it * 256 + tid;
      int row = c >> 3, sl = c & 7, kc = sl ^ (row & 7);
      async_copy16(BT + (size_t)(bn + row) * K + k0 + kc * 8,
                   &lds[buf][(512 + c) * 8]);
    }
  };

  stage(0, 0);
  __syncthreads();
  int cur = 0;
  for (int k0 = 0; k0 < K; k0 += 64) {
    if (k0 + 64 < K) stage(k0 + 64, cur ^ 1);
#pragma unroll
    for (int ks = 0; ks < 2; ++ks) {
      bf16x8 af[2], bfr[4];
#pragma unroll
      for (int mi = 0; mi < 2; ++mi) {
        int row = wm + mi * 16 + lr, kc = ks * 4 + lq;
        af[mi] = *(const bf16x8*)&lds[cur][(row * 8 + (kc ^ (row & 7))) * 8];
      }
#pragma unroll
      for (int ni = 0; ni < 4; ++ni) {
        int row = wn + ni * 16 + lr, kc = ks * 4 + lq;
        bfr[ni] =
            *(const bf16x8*)&lds[cur][(512 + row * 8 + (kc ^ (row & 7))) * 8];
      }
#pragma unroll
      for (int mi = 0; mi < 2; ++mi)
#pragma unroll
        for (int ni = 0; ni < 4; ++ni)
          acc[mi][ni] = __builtin_amdgcn_mfma_f32_16x16x32_bf16(
              af[mi], bfr[ni], acc[mi][ni], 0, 0, 0);
    }
    __syncthreads();
    cur ^= 1;
  }

  const int head = bn >> 7;
  ushort* ep = &lds[0][0];   // 64 x 130 bf16 tile (8320 <= 12288 ushorts)
  if (head < 20) {
    // ---- q/k head: rope via LDS round trip
#pragma unroll
    for (int mi = 0; mi < 2; ++mi)
#pragma unroll
      for (int ni = 0; ni < 4; ++ni)
#pragma unroll
        for (int r = 0; r < 4; ++r)
          ep[(wm + mi * 16 + lq * 4 + r) * 130 + wn + ni * 16 + lr] =
              f2bf(acc[mi][ni][r]);
    __syncthreads();

    const float qs = (head < NH) ? 0.08838834764831845f : 1.0f;
#pragma unroll
    for (int it = 0; it < 16; ++it) {
      int idx = it * 256 + tid;        // 64 rows x 64 pairs
      int row = idx >> 6, j = idx & 63;
      float x1 = bf2f(ep[row * 130 + j]);
      float x2 = bf2f(ep[row * 130 + 64 + j]);
      float2 cs = tbl[(size_t)(bm + row) * 64 + j];
      qkvb[(size_t)(bm + row) * QKV_COLS + bn + j] =
          f2bf((x1 * cs.x - x2 * cs.y) * qs);
      qkvb[(size_t)(bm + row) * QKV_COLS + bn + 64 + j] =
          f2bf((x2 * cs.x + x1 * cs.y) * qs);
    }
  } else {
    // ---- v head: transposed write into vt[vd][t] via LDS round trip
#pragma unroll
    for (int mi = 0; mi < 2; ++mi)
#pragma unroll
      for (int ni = 0; ni < 4; ++ni)
#pragma unroll
        for (int r = 0; r < 4; ++r)
          ep[(wm + mi * 16 + lq * 4 + r) * 130 + wn + ni * 16 + lr] =
              f2bf(acc[mi][ni][r]);
    __syncthreads();

    const int vd0 = bn - 2560;
#pragma unroll
    for (int it = 0; it < 8; ++it) {
      int idx = it * 256 + tid;        // 128 vd x 16 t-groups of 4
      int vd = idx >> 4, tg = (idx & 15) * 4;
      ushort4 w;
      w.x = ep[(tg + 0) * 130 + vd];
      w.y = ep[(tg + 1) * 130 + vd];
      w.z = ep[(tg + 2) * 130 + vd];
      w.w = ep[(tg + 3) * 130 + vd];
      *(ushort4*)&vt[(size_t)(vd0 + vd) * T_LEN + bm + tg] = w;
    }
  }
}

// ---------------------------------------------------------------------------
// Flash attention v7: rebalanced split-K. No block exceeds 12 k-tiles:
//   qt 0..11  : 1 chunk  (direct output)          192 blocks
//   qt 12..23 : 2 chunks (slots 0..383)           384 blocks
//   qt 24..31 : 3 chunks (slots 384..767)         384 blocks
// Heaviest blocks dispatched first. 960 blocks total; 768 partial slots
// exactly fill the 12 MB wqkvT alias. Core loop = R1-best + T5 setprio.
// ---------------------------------------------------------------------------
__global__ __launch_bounds__(256, 3) void attn_mfma(
    const ushort* __restrict__ qkv, const ushort* __restrict__ vt,
    ushort* __restrict__ o, ushort* __restrict__ partials,
    float* __restrict__ ml) {
  int qt, h, k_begin, k_end, slot = -1;
  {
    const int i = blockIdx.x;
    int c = 0, nc = 1;
    if (i < 64) {                    // singles qt 11..8 (work 12..9) first
      qt = 11 - (i >> 4); h = i & 15;
    } else if (i < 448) {            // 2-chunk qt 23..12
      int j = i - 64;
      qt = 23 - (j >> 5);
      int rem = j & 31;
      h = rem >> 1; c = rem & 1; nc = 2;
      slot = ((qt - 12) * 16 + h) * 2 + c;
    } else if (i < 832) {            // 3-chunk qt 31..24
      int j = i - 448;
      qt = 31 - (j / 48);
      int rem = j % 48;
      h = rem / 3; c = rem % 3; nc = 3;
      slot = 384 + ((qt - 24) * 16 + h) * 3 + c;
    } else {                         // singles qt 7..0 (small tail)
      int j = i - 832;
      qt = 7 - (j >> 4); h = j & 15;
    }
    const int n = qt + 1;
    k_begin = (n * c) / nc;
    k_end = (n * (c + 1)) / nc;
  }
  const int kh = h >> 2;
  const int tid = threadIdx.x;
  const int wave = tid >> 6, lane = tid & 63;
  const int lr = lane & 15, lq = lane >> 4;
  const int wq = wave >> 1, ws = wave & 1;

  __shared__ __align__(16) ushort KsL[1024 * 8];
  __shared__ __align__(16) ushort VtsL[1024 * 8];
  __shared__ __align__(16) ushort Ps[8 * 67 * 8];
  __shared__ float l_sh[64][2];

  bf16x8 qf[2][4];
  {
    const ushort* qbase =
        qkv + (size_t)(qt * 64 + wq * 32 + lr) * QKV_COLS + h * HD + lq * 8;
#pragma unroll
    for (int mi = 0; mi < 2; ++mi)
#pragma unroll
      for (int kk = 0; kk < 4; ++kk)
        qf[mi][kk] = *(const bf16x8*)(qbase + (size_t)mi * 16 * QKV_COLS + kk * 32);
  }

  float l_part[2][4];
#pragma unroll
  for (int mi = 0; mi < 2; ++mi)
#pragma unroll
    for (int r = 0; r < 4; ++r) l_part[mi][r] = 0.f;
  f32x4 o_acc[4][2];
#pragma unroll
  for (int qi = 0; qi < 4; ++qi)
#pragma unroll
    for (int di = 0; di < 2; ++di) {
      o_acc[qi][di][0] = 0.f; o_acc[qi][di][1] = 0.f;
      o_acc[qi][di][2] = 0.f; o_acc[qi][di][3] = 0.f;
    }

  for (int kt = k_begin; kt < k_end; ++kt) {
    __syncthreads();

    {
      const ushort* kbase = qkv + 2048 + kh * HD;
#pragma unroll
      for (int it = 0; it < 4; ++it) {
        int c = it * 256 + tid;
        int s = c >> 4, sl = c & 15, dg = sl ^ (s & 15);
        async_copy16(kbase + (size_t)(kt * 64 + s) * QKV_COLS + dg * 8,
                     &KsL[c * 8]);
      }
    }
    {
      const ushort* vbase = vt + (size_t)(kh * HD) * T_LEN + kt * 64;
#pragma unroll
      for (int it = 0; it < 4; ++it) {
        int c = it * 256 + tid;
        int d = c >> 3, sl = c & 7, sc = sl ^ (d & 7);
        async_copy16(vbase + (size_t)d * T_LEN + sc * 8, &VtsL[c * 8]);
      }
    }
    __syncthreads();

    f32x4 s_acc[2][2];
#pragma unroll
    for (int mi = 0; mi < 2; ++mi)
#pragma unroll
      for (int ni = 0; ni < 2; ++ni) {
        s_acc[mi][ni][0] = 0.f; s_acc[mi][ni][1] = 0.f;
        s_acc[mi][ni][2] = 0.f; s_acc[mi][ni][3] = 0.f;
      }
    __builtin_amdgcn_s_setprio(1);
#pragma unroll
    for (int kk = 0; kk < 4; ++kk) {
      bf16x8 kf[2];
#pragma unroll
      for (int ni = 0; ni < 2; ++ni) {
        int s = ws * 32 + ni * 16 + lr;
        kf[ni] = *(const bf16x8*)&KsL[(s * 16 + ((kk * 4 + lq) ^ (s & 15))) * 8];
      }
#pragma unroll
      for (int mi = 0; mi < 2; ++mi)
#pragma unroll
        for (int ni = 0; ni < 2; ++ni)
          s_acc[mi][ni] = __builtin_amdgcn_mfma_f32_16x16x32_bf16(
              qf[mi][kk], kf[ni], s_acc[mi][ni], 0, 0, 0);
    }
    __builtin_amdgcn_s_setprio(0);

    if (kt == qt) {
#pragma unroll
      for (int mi = 0; mi < 2; ++mi)
#pragma unroll
        for (int ni = 0; ni < 2; ++ni)
#pragma unroll
          for (int r = 0; r < 4; ++r)
            if (ws * 32 + ni * 16 + lr > wq * 32 + mi * 16 + lq * 4 + r)
              s_acc[mi][ni][r] = -1e30f;
    }

#pragma unroll
    for (int mi = 0; mi < 2; ++mi)
#pragma unroll
      for (int ni = 0; ni < 2; ++ni)
#pragma unroll
        for (int r = 0; r < 4; ++r) {
          float p = __expf(s_acc[mi][ni][r]);
          l_part[mi][r] += p;
          int s = ws * 32 + ni * 16 + lr;
          int q = wq * 32 + mi * 16 + lq * 4 + r;
          Ps[((s >> 3) * 67 + q) * 8 + (s & 7)] = f2bf(p);
        }
    __syncthreads();

    __builtin_amdgcn_s_setprio(1);
#pragma unroll
    for (int ss = 0; ss < 2; ++ss) {
      bf16x8 vf[2];
#pragma unroll
      for (int di = 0; di < 2; ++di) {
        int d = wave * 32 + di * 16 + lr, sc = ss * 4 + lq;
        vf[di] = *(const bf16x8*)&VtsL[(d * 8 + (sc ^ (d & 7))) * 8];
      }
#pragma unroll
      for (int qi = 0; qi < 4; ++qi) {
        bf16x8 pf = *(const bf16x8*)&Ps[((ss * 4 + lq) * 67 + qi * 16 + lr) * 8];
#pragma unroll
        for (int di = 0; di < 2; ++di)
          o_acc[qi][di] = __builtin_amdgcn_mfma_f32_16x16x32_bf16(
              pf, vf[di], o_acc[qi][di], 0, 0, 0);
      }
    }
    __builtin_amdgcn_s_setprio(0);
  }

#pragma unroll
  for (int mi = 0; mi < 2; ++mi)
#pragma unroll
    for (int r = 0; r < 4; ++r) {
      float v = l_part[mi][r];
#pragma unroll
      for (int off = 1; off < 16; off <<= 1) v += __shfl_xor(v, off, 16);
      l_part[mi][r] = v;
    }
  if (lr == 0) {
#pragma unroll
    for (int mi = 0; mi < 2; ++mi)
#pragma unroll
      for (int r = 0; r < 4; ++r)
        l_sh[wq * 32 + mi * 16 + lq * 4 + r][ws] = l_part[mi][r];
  }
  __syncthreads();

  if (slot < 0) {
    ushort* ob = o + (size_t)(qt * 64) * (NH * HD) + h * HD + wave * 32;
#pragma unroll
    for (int qi = 0; qi < 4; ++qi)
#pragma unroll
      for (int r = 0; r < 4; ++r) {
        int q = qi * 16 + lq * 4 + r;
        float inv = 1.f / (l_sh[q][0] + l_sh[q][1]);
#pragma unroll
        for (int di = 0; di < 2; ++di)
          ob[(size_t)q * (NH * HD) + di * 16 + lr] =
              f2bf(o_acc[qi][di][r] * inv);
      }
  } else {
    ushort* pb = partials + (size_t)slot * 64 * HD + wave * 32;
#pragma unroll
    for (int qi = 0; qi < 4; ++qi)
#pragma unroll
      for (int r = 0; r < 4; ++r) {
        int q = qi * 16 + lq * 4 + r;
#pragma unroll
        for (int di = 0; di < 2; ++di)
          pb[(size_t)q * HD + di * 16 + lr] = f2bf(o_acc[qi][di][r]);
      }
    if (tid < 64) ml[(size_t)slot * 64 + tid] = l_sh[tid][0] + l_sh[tid][1];
  }
}

// ---------------------------------------------------------------------------
// Combine 2 (qt 12..23) or 3 (qt 24..31) key-range chunks (m=0: plain sum).
// Vectorized bf16x8 loads, fp32 accumulate, one normalize.
// ---------------------------------------------------------------------------
__global__ __launch_bounds__(256) void attn_reduce(
    const ushort* __restrict__ partials, const float* __restrict__ ml,
    ushort* __restrict__ o) {
  const int bi = blockIdx.x;
  int qt, h, base, cnt;
  if (bi < 192) {
    qt = 12 + (bi >> 4); h = bi & 15;
    base = ((qt - 12) * 16 + h) * 2; cnt = 2;
  } else {
    int k = bi - 192;
    qt = 24 + (k >> 4); h = k & 15;
    base = 384 + ((qt - 24) * 16 + h) * 3; cnt = 3;
  }
  const int tid = threadIdx.x;
  const int row = tid >> 2;
  const int dq = (tid & 3) * 32;

  float lsum = 0.f;
  for (int c = 0; c < cnt; ++c) lsum += ml[(size_t)(base + c) * 64 + row];
  const float inv = 1.f / lsum;

  float accf[32];
#pragma unroll
  for (int k = 0; k < 32; ++k) accf[k] = 0.f;
  for (int c = 0; c < cnt; ++c) {
    const ushort* p = partials + ((size_t)(base + c) * 64 + row) * HD + dq;
#pragma unroll
    for (int v = 0; v < 4; ++v) {
      bf16x8 a = *(const bf16x8*)(p + v * 8);
#pragma unroll
      for (int k = 0; k < 8; ++k) accf[v * 8 + k] += bf2f((ushort)a[k]);
    }
  }
  ushort* ob = o + (size_t)(qt * 64 + row) * (NH * HD) + h * HD + dq;
#pragma unroll
  for (int v = 0; v < 4; ++v) {
    bf16x8 w;
#pragma unroll
    for (int k = 0; k < 8; ++k)
      w[k] = (short)f2bf(accf[v * 8 + k] * inv);
    *(bf16x8*)(ob + v * 8) = w;
  }
}

// ---------------------------------------------------------------------------
extern "C" void kernel_launch(void* const* d_in, const int* in_sizes, int n_in,
                              void* d_out, int out_size, void* d_ws,
                              size_t ws_size, hipStream_t stream) {
  const float* hidden = (const float*)d_in[0];
  const float* w_qkv  = (const float*)d_in[1];
  const float* w_o    = (const float*)d_in[2];
  const int* positions = (const int*)d_in[3];
  float* out = (float*)d_out;

  ushort* ws = (ushort*)d_ws;
  ushort* hb    = ws;                    // 2048*2048  (dead after gemm1 -> ob)
  ushort* wqkvT = ws + 4194304;          // 3072*2048  (-> partials [768 slots exactly] -> woT fallback)
  ushort* qkvb  = wqkvT + 6291456;       // 2048*3072  (v-cols never written)
  ushort* vtb   = qkvb + 6291456;        // 512*2048
  float*  mlb   = (float*)(vtb + 1048576);        // 768*64 fp32 = 192 KB
  float2* tbl   = (float2*)(mlb + 49152);         // 2048*64 float2 = 1 MB
  ushort* wsend = (ushort*)(tbl + 131072);        // = ws + 18,448,384
  ushort* ob       = hb;
  ushort* partials = wqkvT;

  // Fast path: dedicated 8 MB woT after wsend -> w_o transpose folds into
  // prep (off the critical path). Fallback: alias wqkvT, serialized after
  // attn_reduce (current-best behavior). Branch is deterministic per capture.
  const size_t need_bytes = (18448384ull + 4194304ull) * 2;   // 45.3 MB
  const bool fast = ws_size >= need_bytes;
  ushort* woT = fast ? wsend : wqkvT;

  prep<<<fast ? 7168 : 6144, 256, 0, stream>>>(
      hidden, hb, w_qkv, wqkvT, positions, tbl, w_o, woT);

  gemm_qkv<<<dim3(QKV_COLS / 128, T_LEN / 64), 256, 0, stream>>>(
      hb, wqkvT, qkvb, vtb, tbl, T_LEN, QKV_COLS, HID);

  attn_mfma<<<960, 256, 0, stream>>>(qkvb, vtb, ob, partials, mlb);
  attn_reduce<<<320, 256, 0, stream>>>(partials, mlb, ob);

  if (!fast)
    transpose_cast<<<dim3(HID / 64, HID / 64), 256, 0, stream>>>(
        w_o, woT, HID, HID);

  gemm_bt<false><<<dim3(HID / 128, T_LEN / 64), 256, 0, stream>>>(
      ob, woT, out, T_LEN, HID, NH * HD);
}